// Round 12
// baseline (1435.266 us; speedup 1.0000x reference)
//
#include <hip/hip_runtime.h>
#include <hip/hip_bf16.h>
#include <math.h>

#define N_B 4
#define H_H 12
#define T_T 1024
#define D_H 64
#define F_F 266
#define N_H 48          // N_B*H_H
#define TM_ 128
#define KSEL 98304u     // kk*T*H = 8*1024*12
#define PER_BATCH 1572864  // H*T*TM
#define FCH 14
#define NCH 19          // 19*14 = 266

static __device__ __forceinline__ float waveSum(float v){
  for(int o=32;o;o>>=1) v += __shfl_xor(v,o,64);
  return v;
}
static __device__ __forceinline__ float waveMax(float v){
  for(int o=32;o;o>>=1) v = fmaxf(v,__shfl_xor(v,o,64));
  return v;
}

#define DN_C 0.35355339059327373f   // 64^-0.25 = 2^-1.5
#define DIAG_C 0.0625f              // 0.5 * 64^-0.5
#define RATIO_C 0.06131393394849658f // 266^-0.5
#define EPS_C 1e-4f

// ---------------- Kernel A0: per-(head,t) diag ----------------------------
__global__ __launch_bounds__(256) void diag_kern(
    const float* __restrict__ kfa, float* __restrict__ diags){
  int head = blockIdx.x; int t = blockIdx.y*256 + threadIdx.x;
  const float4* xp = (const float4*)(kfa + ((size_t)head*T_T + t)*D_H);
  float diag = 0.f;
  #pragma unroll
  for(int kk=0;kk<16;kk++){ float4 x = xp[kk];
    diag += x.x*x.x + x.y*x.y + x.z*x.z + x.w*x.w; }
  diags[head*T_T + t] = diag * DIAG_C;
}

// ---------------- Kernel B v4: key features, lane-owns-t-strided ----------
__global__ __launch_bounds__(256) void keyfeat_kern(
    const float* __restrict__ kfa, const float* __restrict__ pm,
    const float* __restrict__ mask, const float* __restrict__ diags,
    float* __restrict__ ctxraw, float* __restrict__ ksumP,
    float* __restrict__ mfP){
  int head = blockIdx.x, fc = blockIdx.y;
  int f0 = fc*FCH;
  int n = head / H_H;
  int lane = threadIdx.x & 63, tq = threadIdx.x >> 6;
  __shared__ float cred[FCH][64];
  __shared__ float kred[4][FCH];
  __shared__ float mred[4];
  float kacc[FCH], cacc[FCH];
  #pragma unroll
  for(int i=0;i<FCH;i++){ kacc[i]=0.f; cacc[i]=0.f; }
  float mymax = -3.4e38f;
  for(int tt=0; tt<4; tt++){
    int tc = tq*4 + tt;
    int t = lane*16 + tc;
    const float4* xp = (const float4*)(kfa + ((size_t)head*T_T + t)*D_H);
    float4 xr[16];
    #pragma unroll
    for(int kk=0;kk<16;kk++) xr[kk] = xp[kk];
    float dg = diags[head*T_T + t];
    float cmul = ((tc < 8) && (mask[n*T_T + t] > -1.0f)) ? 1.f : 0.f;
    for(int fi=0; fi<FCH; fi++){
      const float4* pr = (const float4*)(pm + (size_t)(f0+fi)*D_H);
      float s0=0,s1=0,s2=0,s3=0;
      #pragma unroll
      for(int kk=0;kk<16;kk++){ float4 w4 = pr[kk];
        s0+=xr[kk].x*w4.x; s1+=xr[kk].y*w4.y; s2+=xr[kk].z*w4.z; s3+=xr[kk].w*w4.w; }
      float dd = DN_C*((s0+s1)+(s2+s3));
      mymax = fmaxf(mymax, dd);
      float e = expf(dd - dg);
      kacc[fi] += e;
      cacc[fi] += e*cmul;
    }
  }
  #pragma unroll
  for(int fi=0;fi<FCH;fi++){
    float s = waveSum(kacc[fi]);
    if(lane==0) kred[tq][fi] = s;
  }
  mymax = waveMax(mymax);
  if(lane==0) mred[tq]=mymax;
  if(tq==0){
    #pragma unroll
    for(int fi=0;fi<FCH;fi++) cred[fi][lane] = cacc[fi];
  }
  __syncthreads();
  if(tq==1){
    #pragma unroll
    for(int fi=0;fi<FCH;fi++) cred[fi][lane] += cacc[fi];
  }
  __syncthreads();
  for(int i=threadIdx.x; i<FCH*64; i+=256){
    int fi=i>>6, d=i&63;
    ctxraw[((size_t)head*F_F + f0+fi)*64 + d] = cred[fi][d];
  }
  if(threadIdx.x < FCH)
    ksumP[head*F_F + f0 + threadIdx.x] =
      kred[0][threadIdx.x]+kred[1][threadIdx.x]+kred[2][threadIdx.x]+kred[3][threadIdx.x];
  if(threadIdx.x==0)
    mfP[head*NCH+fc] = fmaxf(fmaxf(mred[0],mred[1]),fmaxf(mred[2],mred[3]));
}

// ---------------- Kernel B2: per-head fixup -------------------------------
__global__ __launch_bounds__(256) void fixup_kern(
    const float* __restrict__ mfP, const float* __restrict__ ksumP,
    const float* __restrict__ ctxraw, const float* __restrict__ mask,
    float* __restrict__ ctx, float* __restrict__ ksum,
    float* __restrict__ ksum_tot, float* __restrict__ ctx_tot){
  int head = blockIdx.x; int n = head/H_H;
  __shared__ float segc[64];
  __shared__ float part[4][64];
  __shared__ float kpart[4];
  float m_head = mfP[head*NCH];
  for(int i=1;i<NCH;i++) m_head = fmaxf(m_head, mfP[head*NCH+i]);
  float e_mh = expf(-m_head);
  if(threadIdx.x < 64){
    int d = threadIdx.x; float c=0.f;
    for(int i=0;i<8;i++) c += (mask[n*T_T + 16*d + i] > -1.0f) ? 1.f : 0.f;
    segc[d] = c;
  }
  __syncthreads();
  int g = threadIdx.x>>6, d = threadIdx.x&63;
  float ct = 0.f, kt = 0.f;
  for(int f=g; f<F_F; f+=4){
    float craw = ctxraw[((size_t)head*F_F+f)*64 + d];
    float cf = RATIO_C*(craw*e_mh + EPS_C*segc[d]);
    ctx[((size_t)head*F_F+f)*64 + d] = cf;
    ct += cf;
    if(d==0){
      float kf = RATIO_C*(ksumP[head*F_F+f]*e_mh + EPS_C*(float)T_T);
      ksum[head*F_F+f] = kf;
      kt += kf;
    }
  }
  part[g][d] = ct;
  if(d==0) kpart[g] = kt;
  __syncthreads();
  if(threadIdx.x < 64)
    ctx_tot[head*64+threadIdx.x] =
      part[0][threadIdx.x]+part[1][threadIdx.x]+part[2][threadIdx.x]+part[3][threadIdx.x];
  if(threadIdx.x==0) ksum_tot[head] = kpart[0]+kpart[1]+kpart[2]+kpart[3];
}

// ---------------- Kernel C v4: query features + pcl (deferred max) --------
// (reverted to R10 version — known 133 us; v5 wave-uniform variant regressed)
__global__ __launch_bounds__(256) void qfeat_kern(
    const float* __restrict__ qfa, const float* __restrict__ pm,
    const float* __restrict__ ctx, const float* __restrict__ ksum,
    const float* __restrict__ ksum_tot, const float* __restrict__ ctx_tot,
    float* __restrict__ pcl){
  int head = blockIdx.x, tc = blockIdx.y;   // grid (48,16), 256 threads
  int rl = threadIdx.x >> 2, fs = threadIdx.x & 3;
  int t = tc*64 + rl;
  __shared__ float pms[56*68];
  __shared__ float ctxs[56*68];
  __shared__ float ksums[56];
  const float* xp = qfa + ((size_t)head*T_T + t)*D_H;
  float4 xr[16];
  #pragma unroll
  for(int kk=0;kk<16;kk++) xr[kk] = ((const float4*)xp)[kk];
  float diag = 0.f;
  #pragma unroll
  for(int kk=0;kk<16;kk++)
    diag += xr[kk].x*xr[kk].x + xr[kk].y*xr[kk].y + xr[kk].z*xr[kk].z + xr[kk].w*xr[kk].w;
  diag *= DIAG_C;
  float m_run = -3.4e38f, m_acc = 0.f, S = 0.f;
  bool first = true;
  float4 acc[16];
  #pragma unroll
  for(int kk=0;kk<16;kk++) acc[kk] = make_float4(0.f,0.f,0.f,0.f);
  for(int c=0;c<5;c++){
    int f0 = c*56, CF = min(56, F_F-f0);
    __syncthreads();
    for(int i=threadIdx.x;i<CF*16;i+=256){
      int fl=i>>4, d4=i&15;
      ((float4*)(pms+fl*68))[d4]  = ((const float4*)(pm+(size_t)(f0+fl)*64))[d4];
      ((float4*)(ctxs+fl*68))[d4] = ((const float4*)(ctx+((size_t)head*F_F+f0+fl)*64))[d4];
    }
    for(int i=threadIdx.x;i<CF;i+=256) ksums[i]=ksum[head*F_F+f0+i];
    __syncthreads();
    int nj = (CF - fs + 3)>>2;
    for(int j=0;j<nj;j++){
      int fl = fs+4*j;
      const float4* pr = (const float4*)(pms + fl*68);
      float s0=0,s1=0,s2=0,s3=0;
      #pragma unroll
      for(int kk=0;kk<16;kk++){ float4 w4 = pr[kk];
        s0+=xr[kk].x*w4.x; s1+=xr[kk].y*w4.y; s2+=xr[kk].z*w4.z; s3+=xr[kk].w*w4.w; }
      float dd = DN_C*((s0+s1)+(s2+s3));
      if(first){ m_acc = dd; first = false; }
      m_run = fmaxf(m_run, dd);
      float e = expf(dd - diag - m_acc);
      S += e * ksums[fl];
      const float4* cr = (const float4*)(ctxs + fl*68);
      #pragma unroll
      for(int kk=0;kk<16;kk++){ float4 c4=cr[kk];
        acc[kk].x+=e*c4.x; acc[kk].y+=e*c4.y; acc[kk].z+=e*c4.z; acc[kk].w+=e*c4.w; }
    }
  }
  // single deferred rescale to m_run base
  {
    float fac = expf(m_acc - m_run);
    S *= fac;
    #pragma unroll
    for(int kk=0;kk<16;kk++){
      acc[kk].x*=fac; acc[kk].y*=fac; acc[kk].z*=fac; acc[kk].w*=fac;
    }
  }
  // combine the 4 f-slices with max-rescale (butterfly)
  for(int st=1; st<=2; st<<=1){
    float mo = __shfl_xor(m_run, st, 64);
    float mc = fmaxf(m_run, mo);
    float fac = expf(m_run - mc);
    S *= fac;
    S += __shfl_xor(S, st, 64);
    #pragma unroll
    for(int kk=0;kk<16;kk++){
      acc[kk].x*=fac; acc[kk].y*=fac; acc[kk].z*=fac; acc[kk].w*=fac;
    }
    #pragma unroll
    for(int kk=0;kk<16;kk++){
      acc[kk].x += __shfl_xor(acc[kk].x,st,64);
      acc[kk].y += __shfl_xor(acc[kk].y,st,64);
      acc[kk].z += __shfl_xor(acc[kk].z,st,64);
      acc[kk].w += __shfl_xor(acc[kk].w,st,64);
    }
    m_run = mc;
  }
  float den = S + EPS_C * ksum_tot[head];
  float dinv = 1.0f/den;
  float4 w0,w1,w2,w3;
  if(fs==0){ w0=acc[0]; w1=acc[1]; w2=acc[2]; w3=acc[3]; }
  else if(fs==1){ w0=acc[4]; w1=acc[5]; w2=acc[6]; w3=acc[7]; }
  else if(fs==2){ w0=acc[8]; w1=acc[9]; w2=acc[10]; w3=acc[11]; }
  else { w0=acc[12]; w1=acc[13]; w2=acc[14]; w3=acc[15]; }
  const float4* ctp = ((const float4*)(ctx_tot + head*64)) + fs*4;
  float4 c0=ctp[0], c1=ctp[1], c2=ctp[2], c3=ctp[3];
  float4* po = (float4*)(pcl + ((size_t)head*T_T + t)*D_H) + fs*4;
  po[0] = make_float4((w0.x+EPS_C*c0.x)*dinv,(w0.y+EPS_C*c0.y)*dinv,(w0.z+EPS_C*c0.z)*dinv,(w0.w+EPS_C*c0.w)*dinv);
  po[1] = make_float4((w1.x+EPS_C*c1.x)*dinv,(w1.y+EPS_C*c1.y)*dinv,(w1.z+EPS_C*c1.z)*dinv,(w1.w+EPS_C*c1.w)*dinv);
  po[2] = make_float4((w2.x+EPS_C*c2.x)*dinv,(w2.y+EPS_C*c2.y)*dinv,(w2.z+EPS_C*c2.z)*dinv,(w2.w+EPS_C*c2.w)*dinv);
  po[3] = make_float4((w3.x+EPS_C*c3.x)*dinv,(w3.y+EPS_C*c3.y)*dinv,(w3.z+EPS_C*c3.z)*dinv,(w3.w+EPS_C*c3.w)*dinv);
}

// ---------------- Kernel D: MLP + LN + GELU + score + softmax -------------
#define FMA4(A,s,W) {A.x+=(s)*W.x; A.y+=(s)*W.y; A.z+=(s)*W.z; A.w+=(s)*W.w;}
__global__ __launch_bounds__(256) void mlp_kern(
    const float* __restrict__ pcl, const float* __restrict__ v,
    const float* __restrict__ mask,
    const float* __restrict__ encw, const float* __restrict__ encb,
    const float* __restrict__ lng, const float* __restrict__ lnb,
    const float* __restrict__ decw, const float* __restrict__ decb,
    float* __restrict__ probsout, float* __restrict__ scoreout){
  int head = blockIdx.x, tblk = blockIdx.y;   // grid (48,32)
  int t0 = tblk*32;
  int n = head / H_H;
  __shared__ float xs[32*132];
  __shared__ float wts[32*132];
  __shared__ float h1s[32*132];
  int colT = threadIdx.x & 15, rowT = threadIdx.x >> 4;
  int r0 = rowT, r1 = rowT + 16;
  const float* pclrow = pcl + ((size_t)head*T_T + t0)*D_H;
  const float* vrow   = v   + ((size_t)head*T_T + t0)*D_H;
  for(int i=threadIdx.x;i<512;i+=256){
    int r=i>>4, q=i&15;
    ((float4*)(xs + r*132))[q]      = ((const float4*)(pclrow + r*64))[q];
    ((float4*)(xs + r*132 + 64))[q] = ((const float4*)(vrow   + r*64))[q];
  }
  float4 bias0 = ((const float4*)encb)[colT];
  float4 bias1 = ((const float4*)encb)[colT+16];
  float4 A0=bias0, A1=bias1, B0=bias0, B1=bias1;
  for(int kc=0;kc<4;kc++){
    __syncthreads();
    for(int i=threadIdx.x;i<1024;i+=256){
      int k=i>>5, q=i&31;
      ((float4*)(wts + k*132))[q] = ((const float4*)(encw + (size_t)(kc*32+k)*128))[q];
    }
    __syncthreads();
    #pragma unroll
    for(int kq=0;kq<8;kq++){
      float4 x0 = ((const float4*)(xs + r0*132 + kc*32))[kq];
      float4 x1 = ((const float4*)(xs + r1*132 + kc*32))[kq];
      #pragma unroll
      for(int kk=0;kk<4;kk++){
        const float* wrow = wts + (kq*4+kk)*132;
        float4 wa = ((const float4*)wrow)[colT];
        float4 wb = ((const float4*)wrow)[colT+16];
        float xv0 = (kk==0)?x0.x:(kk==1)?x0.y:(kk==2)?x0.z:x0.w;
        float xv1 = (kk==0)?x1.x:(kk==1)?x1.y:(kk==2)?x1.z:x1.w;
        FMA4(A0,xv0,wa); FMA4(A1,xv0,wb);
        FMA4(B0,xv1,wa); FMA4(B1,xv1,wb);
      }
    }
  }
  float4 lg0 = ((const float4*)lng)[colT], lg1 = ((const float4*)lng)[colT+16];
  float4 lb0 = ((const float4*)lnb)[colT], lb1 = ((const float4*)lnb)[colT+16];
  float s0 = A0.x+A0.y+A0.z+A0.w + A1.x+A1.y+A1.z+A1.w;
  float s1 = B0.x+B0.y+B0.z+B0.w + B1.x+B1.y+B1.z+B1.w;
  for(int o=1;o<16;o<<=1){ s0 += __shfl_xor(s0,o,64); s1 += __shfl_xor(s1,o,64); }
  float mu0 = s0*(1.0f/128.0f), mu1 = s1*(1.0f/128.0f);
  float v0=0.f, v1=0.f;
  { float d;
    d=A0.x-mu0; v0+=d*d; d=A0.y-mu0; v0+=d*d; d=A0.z-mu0; v0+=d*d; d=A0.w-mu0; v0+=d*d;
    d=A1.x-mu0; v0+=d*d; d=A1.y-mu0; v0+=d*d; d=A1.z-mu0; v0+=d*d; d=A1.w-mu0; v0+=d*d;
    d=B0.x-mu1; v1+=d*d; d=B0.y-mu1; v1+=d*d; d=B0.z-mu1; v1+=d*d; d=B0.w-mu1; v1+=d*d;
    d=B1.x-mu1; v1+=d*d; d=B1.y-mu1; v1+=d*d; d=B1.z-mu1; v1+=d*d; d=B1.w-mu1; v1+=d*d; }
  for(int o=1;o<16;o<<=1){ v0 += __shfl_xor(v0,o,64); v1 += __shfl_xor(v1,o,64); }
  float den0 = sqrtf(v0*(1.0f/128.0f)+1e-5f);
  float den1 = sqrtf(v1*(1.0f/128.0f)+1e-5f);
  #define GELU(x) ((x)*0.5f*(1.0f+erff((x)*0.70710678118654752f)))
  #define LNG(a,mu,dn,g,b) GELU(((a)-(mu))/(dn)*(g)+(b))
  float4 H;
  H.x=LNG(A0.x,mu0,den0,lg0.x,lb0.x); H.y=LNG(A0.y,mu0,den0,lg0.y,lb0.y);
  H.z=LNG(A0.z,mu0,den0,lg0.z,lb0.z); H.w=LNG(A0.w,mu0,den0,lg0.w,lb0.w);
  ((float4*)(h1s + r0*132))[colT] = H;
  H.x=LNG(A1.x,mu0,den0,lg1.x,lb1.x); H.y=LNG(A1.y,mu0,den0,lg1.y,lb1.y);
  H.z=LNG(A1.z,mu0,den0,lg1.z,lb1.z); H.w=LNG(A1.w,mu0,den0,lg1.w,lb1.w);
  ((float4*)(h1s + r0*132))[colT+16] = H;
  H.x=LNG(B0.x,mu1,den1,lg0.x,lb0.x); H.y=LNG(B0.y,mu1,den1,lg0.y,lb0.y);
  H.z=LNG(B0.z,mu1,den1,lg0.z,lb0.z); H.w=LNG(B0.w,mu1,den1,lg0.w,lb0.w);
  ((float4*)(h1s + r1*132))[colT] = H;
  H.x=LNG(B1.x,mu1,den1,lg1.x,lb1.x); H.y=LNG(B1.y,mu1,den1,lg1.y,lb1.y);
  H.z=LNG(B1.z,mu1,den1,lg1.z,lb1.z); H.w=LNG(B1.w,mu1,den1,lg1.w,lb1.w);
  ((float4*)(h1s + r1*132))[colT+16] = H;
  bias0 = ((const float4*)decb)[colT];
  bias1 = ((const float4*)decb)[colT+16];
  A0=bias0; A1=bias1; B0=bias0; B1=bias1;
  for(int kc=0;kc<4;kc++){
    __syncthreads();
    for(int i=threadIdx.x;i<1024;i+=256){
      int k=i>>5, q=i&31;
      ((float4*)(wts + k*132))[q] = ((const float4*)(decw + (size_t)(kc*32+k)*128))[q];
    }
    __syncthreads();
    #pragma unroll
    for(int kq=0;kq<8;kq++){
      float4 x0 = ((const float4*)(h1s + r0*132 + kc*32))[kq];
      float4 x1 = ((const float4*)(h1s + r1*132 + kc*32))[kq];
      #pragma unroll
      for(int kk=0;kk<4;kk++){
        const float* wrow = wts + (kq*4+kk)*132;
        float4 wa = ((const float4*)wrow)[colT];
        float4 wb = ((const float4*)wrow)[colT+16];
        float xv0 = (kk==0)?x0.x:(kk==1)?x0.y:(kk==2)?x0.z:x0.w;
        float xv1 = (kk==0)?x1.x:(kk==1)?x1.y:(kk==2)?x1.z:x1.w;
        FMA4(A0,xv0,wa); FMA4(A1,xv0,wb);
        FMA4(B0,xv1,wa); FMA4(B1,xv1,wb);
      }
    }
  }
  const float* mrow = mask + n*T_T;
  int c0 = colT*4, c1 = colT*4 + 64;
  float rm0[4], rm1[4];
  #pragma unroll
  for(int i=0;i<4;i++){ rm0[i]=mrow[(c0+i)*8]; rm1[i]=mrow[(c1+i)*8]; }
  float sA[8], sB[8];
  sA[0]=(rm0[0]<-1.f)?-10000.f:A0.x; sA[1]=(rm0[1]<-1.f)?-10000.f:A0.y;
  sA[2]=(rm0[2]<-1.f)?-10000.f:A0.z; sA[3]=(rm0[3]<-1.f)?-10000.f:A0.w;
  sA[4]=(rm1[0]<-1.f)?-10000.f:A1.x; sA[5]=(rm1[1]<-1.f)?-10000.f:A1.y;
  sA[6]=(rm1[2]<-1.f)?-10000.f:A1.z; sA[7]=(rm1[3]<-1.f)?-10000.f:A1.w;
  sB[0]=(rm0[0]<-1.f)?-10000.f:B0.x; sB[1]=(rm0[1]<-1.f)?-10000.f:B0.y;
  sB[2]=(rm0[2]<-1.f)?-10000.f:B0.z; sB[3]=(rm0[3]<-1.f)?-10000.f:B0.w;
  sB[4]=(rm1[0]<-1.f)?-10000.f:B1.x; sB[5]=(rm1[1]<-1.f)?-10000.f:B1.y;
  sB[6]=(rm1[2]<-1.f)?-10000.f:B1.z; sB[7]=(rm1[3]<-1.f)?-10000.f:B1.w;
  float mx0=sA[0], mx1=sB[0];
  #pragma unroll
  for(int i=1;i<8;i++){ mx0=fmaxf(mx0,sA[i]); mx1=fmaxf(mx1,sB[i]); }
  for(int o=1;o<16;o<<=1){ mx0=fmaxf(mx0,__shfl_xor(mx0,o,64)); mx1=fmaxf(mx1,__shfl_xor(mx1,o,64)); }
  float Z0=0.f, Z1=0.f;
  #pragma unroll
  for(int i=0;i<8;i++){ sA[i]=expf(sA[i]-mx0); Z0+=sA[i]; sB[i]=expf(sB[i]-mx1); Z1+=sB[i]; }
  for(int o=1;o<16;o<<=1){ Z0+=__shfl_xor(Z0,o,64); Z1+=__shfl_xor(Z1,o,64); }
  float zi0=1.0f/Z0, zi1=1.0f/Z1;
  size_t rb0 = ((size_t)head*T_T + t0 + r0)*TM_;
  size_t rb1 = ((size_t)head*T_T + t0 + r1)*TM_;
  ((float4*)(probsout+rb0))[colT]    = make_float4(sA[0]*zi0,sA[1]*zi0,sA[2]*zi0,sA[3]*zi0);
  ((float4*)(probsout+rb0))[colT+16] = make_float4(sA[4]*zi0,sA[5]*zi0,sA[6]*zi0,sA[7]*zi0);
  ((float4*)(probsout+rb1))[colT]    = make_float4(sB[0]*zi1,sB[1]*zi1,sB[2]*zi1,sB[3]*zi1);
  ((float4*)(probsout+rb1))[colT+16] = make_float4(sB[4]*zi1,sB[5]*zi1,sB[6]*zi1,sB[7]*zi1);
  ((float4*)(scoreout+rb0))[colT]    = A0;
  ((float4*)(scoreout+rb0))[colT+16] = A1;
  ((float4*)(scoreout+rb1))[colT]    = B0;
  ((float4*)(scoreout+rb1))[colT+16] = B1;
}

// ---------------- Kernel E v3: per-row KL + MSE, register-resident --------
__global__ __launch_bounds__(256) void loss_kern(
    const float* __restrict__ truth, const float* __restrict__ mask,
    const float* __restrict__ score, float* __restrict__ klrow,
    float* __restrict__ mserow){
  int row = blockIdx.x;               // head*1024 + t
  int n = row / (H_H*T_T);
  int t = threadIdx.x;
  int lane = t & 63, tq = t >> 6;
  __shared__ float sc[128];
  __shared__ float red[8];
  float4 av  = ((const float4*)(truth + (size_t)row*T_T))[t];
  float4 mkv = ((const float4*)(mask + (size_t)n*T_T))[t];
  if(t < 128) sc[t] = score[(size_t)row*TM_ + t];
  __syncthreads();
  float scv = sc[t>>1];
  float ma = fmaxf(fmaxf(av.x+mkv.x, av.y+mkv.y), fmaxf(av.z+mkv.z, av.w+mkv.w));
  float ms = scv + fmaxf(fmaxf(mkv.x, mkv.y), fmaxf(mkv.z, mkv.w));
  for(int o=32;o;o>>=1){ ma=fmaxf(ma,__shfl_xor(ma,o,64)); ms=fmaxf(ms,__shfl_xor(ms,o,64)); }
  if(lane==0){ red[tq]=ma; red[4+tq]=ms; }
  __syncthreads();
  ma = fmaxf(fmaxf(red[0],red[1]),fmaxf(red[2],red[3]));
  ms = fmaxf(fmaxf(red[4],red[5]),fmaxf(red[6],red[7]));
  __syncthreads();
  float e0=__expf(av.x+mkv.x-ma), e1=__expf(av.y+mkv.y-ma),
        e2=__expf(av.z+mkv.z-ma), e3=__expf(av.w+mkv.w-ma);
  float Za = (e0+e1)+(e2+e3);
  float Zs = (__expf(scv+mkv.x-ms)+__expf(scv+mkv.y-ms))
           + (__expf(scv+mkv.z-ms)+__expf(scv+mkv.w-ms));
  for(int o=32;o;o>>=1){ Za+=__shfl_xor(Za,o,64); Zs+=__shfl_xor(Zs,o,64); }
  if(lane==0){ red[tq]=Za; red[4+tq]=Zs; }
  __syncthreads();
  Za = (red[0]+red[1])+(red[2]+red[3]);
  Zs = (red[4]+red[5])+(red[6]+red[7]);
  __syncthreads();
  float lZs = __logf(Zs), lZa = __logf(Za);
  float invZa = 1.0f/Za;
  float kl=0.f, mse=0.f;
  #define LKL(AJ,MKJ,EJ) { \
    if((MKJ) > -1.0f){ \
      float pt = (EJ)*invZa; \
      float logpt = (pt >= 1e-12f) ? ((AJ)+(MKJ)-ma-lZa) : -27.631021116f; \
      float logp = (scv+(MKJ)-ms) - lZs; \
      kl += pt*(logpt-logp); } \
    float sv = ((MKJ) < -1.0f)?0.f:scv; \
    float avv = ((MKJ) < -1.0f)?0.f:(AJ); \
    float dd = sv-avv; mse += dd*dd; }
  LKL(av.x,mkv.x,e0) LKL(av.y,mkv.y,e1) LKL(av.z,mkv.z,e2) LKL(av.w,mkv.w,e3)
  #undef LKL
  for(int o=32;o;o>>=1){ kl+=__shfl_xor(kl,o,64); mse+=__shfl_xor(mse,o,64); }
  if(lane==0){ red[tq]=kl; red[4+tq]=mse; }
  __syncthreads();
  if(t==0){
    klrow[row]  = (red[0]+red[1])+(red[2]+red[3]);
    mserow[row] = (red[4]+red[5])+(red[6]+red[7]);
  }
}

// ---------------- Kernel F: final loss ------------------------------------
__global__ __launch_bounds__(256) void finloss_kern(
    const float* __restrict__ klrow, const float* __restrict__ mserow,
    const float* __restrict__ mask, float* __restrict__ out0){
  __shared__ double reds[256];
  double kls=0, mses=0;
  for(int i=threadIdx.x;i<N_H*T_T;i+=256){ kls+=(double)klrow[i]; mses+=(double)mserow[i]; }
  double vcnt=0;
  for(int i=threadIdx.x;i<N_B*T_T;i+=256) if(mask[i] > -1.0f) vcnt+=1.0;
  reds[threadIdx.x]=kls; __syncthreads();
  for(int o=128;o;o>>=1){ if(threadIdx.x<o) reds[threadIdx.x]+=reds[threadIdx.x+o]; __syncthreads(); }
  double klsum = reds[0]; __syncthreads();
  reds[threadIdx.x]=mses; __syncthreads();
  for(int o=128;o;o>>=1){ if(threadIdx.x<o) reds[threadIdx.x]+=reds[threadIdx.x+o]; __syncthreads(); }
  double msesum = reds[0]; __syncthreads();
  reds[threadIdx.x]=vcnt; __syncthreads();
  for(int o=128;o;o>>=1){ if(threadIdx.x<o) reds[threadIdx.x]+=reds[threadIdx.x+o]; __syncthreads(); }
  if(threadIdx.x==0){
    double denom = reds[0] * (double)(H_H*T_T);
    double loss = klsum/denom*0.25 + msesum/((double)N_B*H_H*T_T*T_T);
    out0[0]=(float)loss;
  }
}

// ---------------- Top-k pipeline (2 x 16-bit radix levels) ----------------
__global__ __launch_bounds__(256) void topk_init16(
    unsigned* __restrict__ hist, unsigned* __restrict__ state,
    unsigned* __restrict__ tiecnt){
  size_t i = (size_t)blockIdx.x*256 + threadIdx.x;
  if(i < (size_t)4*65536) hist[i]=0u;
  if(i < 4){ state[i*4+0]=0u; state[i*4+1]=KSEL; tiecnt[i]=0u; }
}

__global__ __launch_bounds__(256) void topk_hist16(
    const float* __restrict__ probs, const float* __restrict__ mask,
    const unsigned* __restrict__ state, unsigned* __restrict__ hist, int level){
  unsigned pref[4];
  for(int b=0;b<4;b++) pref[b] = state[b*4+0] >> 16;
  size_t total = (size_t)N_B*PER_BATCH;
  for(size_t idx = (size_t)blockIdx.x*256+threadIdx.x; idx < total; idx += (size_t)gridDim.x*256){
    int b = (int)(idx / PER_BATCH);
    unsigned r = (unsigned)(idx - (size_t)b*PER_BATCH);
    int t = (int)((r>>7)&1023u);
    float val = probs[idx];
    if(!(mask[b*T_T+t] > -1.0f)) val = 0.0f;
    unsigned u = __float_as_uint(val);
    if(level==0){
      atomicAdd(&hist[(size_t)b*65536 + (u>>16)], 1u);
    } else {
      if((u>>16) == pref[b])
        atomicAdd(&hist[(size_t)b*65536 + (u & 0xFFFFu)], 1u);
    }
  }
}

__global__ __launch_bounds__(256) void topk_scan16(
    unsigned* __restrict__ hist, unsigned* __restrict__ state, int level){
  int b = blockIdx.x;
  unsigned* h = hist + (size_t)b*65536;
  __shared__ unsigned cs[256];
  unsigned s = 0;
  for(int i=0;i<256;i++) s += h[threadIdx.x*256 + i];
  cs[threadIdx.x] = s;
  __syncthreads();
  if(threadIdx.x==0){
    unsigned remk = state[b*4+1];
    unsigned cum = 0; int sc = 0;
    for(int c=255;c>=0;c--){
      unsigned cc = cs[c];
      if(remk <= cum + cc){ sc = c; break; }
      cum += cc;
    }
    unsigned sb = 0;
    for(int bb=255;bb>=0;bb--){
      unsigned cc = h[sc*256+bb];
      if(remk <= cum + cc){ sb = (unsigned)bb; break; }
      cum += cc;
    }
    unsigned bin16 = (unsigned)sc*256u + sb;
    if(level==0) state[b*4+0] = bin16 << 16;
    else         state[b*4+0] |= bin16;
    state[b*4+1] = remk - cum;
  }
  __syncthreads();
  // zero histogram for the next pass
  for(int i=threadIdx.x;i<65536;i+=256) h[i]=0u;
}

__global__ __launch_bounds__(256) void topk_write(
    const float* __restrict__ probs, const float* __restrict__ mask,
    const unsigned* __restrict__ state, float* __restrict__ pam,
    unsigned* __restrict__ ties, unsigned* __restrict__ tiecnt){
  unsigned thr[4];
  for(int b=0;b<4;b++) thr[b]=state[b*4+0];
  size_t total=(size_t)N_B*PER_BATCH;
  for(size_t idx=(size_t)blockIdx.x*256+threadIdx.x; idx<total; idx += (size_t)gridDim.x*256){
    int b = (int)(idx / PER_BATCH);
    unsigned r = (unsigned)(idx - (size_t)b*PER_BATCH);
    int t = (int)((r>>7)&1023u);
    float val = probs[idx];
    if(!(mask[b*T_T+t] > -1.0f)) val=0.0f;
    unsigned u=__float_as_uint(val);
    float o = -10000.0f;
    if(u > thr[b]) o = 0.0f;
    else if(u == thr[b]){
      unsigned pos = atomicAdd(&tiecnt[b],1u);
      if(pos < 65536u) ties[(size_t)b*65536+pos]=r;
    }
    pam[idx]=o;
  }
}

__global__ __launch_bounds__(256) void topk_ties(
    const unsigned* __restrict__ state, const unsigned* __restrict__ ties,
    const unsigned* __restrict__ tiecnt, float* __restrict__ pam){
  int b = blockIdx.x;
  unsigned needed = state[b*4+1];
  unsigned nt = min(tiecnt[b], 65536u);
  __shared__ unsigned redu[256];
  __shared__ unsigned lohi[2];
  if(threadIdx.x==0){ lohi[0]=0u; lohi[1]=PER_BATCH; }
  __syncthreads();
  if(needed == 0 || nt == 0) return;
  while(true){
    __syncthreads();
    unsigned lo=lohi[0], hi=lohi[1];
    if(hi-lo<=1u) break;
    unsigned mid=(lo+hi)>>1;
    unsigned c=0;
    for(unsigned i=threadIdx.x;i<nt;i+=256) c += (ties[(size_t)b*65536+i] < mid)?1u:0u;
    redu[threadIdx.x]=c; __syncthreads();
    for(int o=128;o;o>>=1){ if(threadIdx.x<o) redu[threadIdx.x]+=redu[threadIdx.x+o]; __syncthreads(); }
    if(threadIdx.x==0){ if(redu[0]>=needed) lohi[1]=mid; else lohi[0]=mid; }
  }
  __syncthreads();
  unsigned X=lohi[1];
  for(unsigned i=threadIdx.x;i<nt;i+=256){
    unsigned r=ties[(size_t)b*65536+i];
    if(r < X) pam[(size_t)b*PER_BATCH + r]=0.0f;
  }
}

// ---------------- launcher ------------------------------------------------
extern "C" void kernel_launch(void* const* d_in, const int* in_sizes, int n_in,
                              void* d_out, int out_size, void* d_ws, size_t ws_size,
                              hipStream_t stream) {
  const float* v     = (const float*)d_in[2];
  const float* qfa   = (const float*)d_in[3];
  const float* kfa   = (const float*)d_in[4];
  const float* mask  = (const float*)d_in[8];
  const float* truth = (const float*)d_in[9];
  const float* pm    = (const float*)d_in[11];
  const float* encw  = (const float*)d_in[12];
  const float* encb  = (const float*)d_in[13];
  const float* lng   = (const float*)d_in[14];
  const float* lnb   = (const float*)d_in[15];
  const float* decw  = (const float*)d_in[16];
  const float* decb  = (const float*)d_in[17];
  float* out = (float*)d_out;
  float* ws  = (float*)d_ws;

  float* ctx     = ws;                              // 817152
  float* ksum    = ctx + (size_t)N_H*F_F*64;        // 12768
  float* klrow   = ksum + N_H*F_F;                  // 49152
  float* mserow  = klrow + N_H*T_T;                 // 49152
  unsigned* hist16 = (unsigned*)(mserow + N_H*T_T); // 4*65536 = 262144
  unsigned* state  = hist16 + (size_t)4*65536;      // 16
  unsigned* tiecnt = state + 16;                    // 4 (+pad)
  unsigned* ties   = tiecnt + 12;                   // 4*65536
  float* diags   = (float*)(ties + (size_t)4*65536);// 49152
  float* ctxraw  = diags + N_H*T_T;                 // 817152
  float* ksumP   = ctxraw + (size_t)N_H*F_F*64;     // 12768
  float* mfP     = ksumP + N_H*F_F;                 // 912 (+pad)
  float* ksum_tot= mfP + 1024;                      // 48
  float* ctx_tot = ksum_tot + 48;                   // 3072

  float* pcl   = out + 1;
  float* probs = pcl + (size_t)N_H*T_T*D_H;
  float* pam   = probs + (size_t)N_H*T_T*TM_;

  diag_kern<<<dim3(N_H,4),256,0,stream>>>(kfa, diags);
  keyfeat_kern<<<dim3(N_H,NCH),256,0,stream>>>(kfa, pm, mask, diags, ctxraw, ksumP, mfP);
  fixup_kern<<<N_H,256,0,stream>>>(mfP, ksumP, ctxraw, mask, ctx, ksum, ksum_tot, ctx_tot);
  qfeat_kern<<<dim3(N_H,16),256,0,stream>>>(qfa, pm, ctx, ksum, ksum_tot, ctx_tot, pcl);
  mlp_kern<<<dim3(N_H,32),256,0,stream>>>(pcl, v, mask, encw, encb, lng, lnb,
                                          decw, decb, probs, pam /*score*/);
  loss_kern<<<N_H*T_T,256,0,stream>>>(truth, mask, pam /*score*/, klrow, mserow);
  finloss_kern<<<1,256,0,stream>>>(klrow, mserow, mask, out);
  topk_init16<<<1024,256,0,stream>>>(hist16, state, tiecnt);
  topk_hist16<<<2048,256,0,stream>>>(probs, mask, state, hist16, 0);
  topk_scan16<<<4,256,0,stream>>>(hist16, state, 0);
  topk_hist16<<<2048,256,0,stream>>>(probs, mask, state, hist16, 1);
  topk_scan16<<<4,256,0,stream>>>(hist16, state, 1);
  topk_write<<<2048,256,0,stream>>>(probs, mask, state, pam, ties, tiecnt);
  topk_ties<<<4,256,0,stream>>>(state, ties, tiecnt, pam);
}

// Round 13
// 580.750 us; speedup vs baseline: 2.4714x; 2.4714x over previous
//
#include <hip/hip_runtime.h>
#include <hip/hip_bf16.h>
#include <math.h>

#define N_B 4
#define H_H 12
#define T_T 1024
#define D_H 64
#define F_F 266
#define N_H 48          // N_B*H_H
#define TM_ 128
#define KSEL 98304u     // kk*T*H = 8*1024*12
#define PER_BATCH 1572864  // H*T*TM
#define FCH 14
#define NCH 19          // 19*14 = 266

static __device__ __forceinline__ float waveSum(float v){
  for(int o=32;o;o>>=1) v += __shfl_xor(v,o,64);
  return v;
}
static __device__ __forceinline__ float waveMax(float v){
  for(int o=32;o;o>>=1) v = fmaxf(v,__shfl_xor(v,o,64));
  return v;
}

#define DN_C 0.35355339059327373f   // 64^-0.25 = 2^-1.5
#define DIAG_C 0.0625f              // 0.5 * 64^-0.5
#define RATIO_C 0.06131393394849658f // 266^-0.5
#define EPS_C 1e-4f

// ---------------- Kernel B v4: key features, lane-owns-t-strided ----------
// diag folded in (bitwise-identical float4 expression; diag_kern deleted)
__global__ __launch_bounds__(256) void keyfeat_kern(
    const float* __restrict__ kfa, const float* __restrict__ pm,
    const float* __restrict__ mask,
    float* __restrict__ ctxraw, float* __restrict__ ksumP,
    float* __restrict__ mfP){
  int head = blockIdx.x, fc = blockIdx.y;
  int f0 = fc*FCH;
  int n = head / H_H;
  int lane = threadIdx.x & 63, tq = threadIdx.x >> 6;
  __shared__ float cred[FCH][64];
  __shared__ float kred[4][FCH];
  __shared__ float mred[4];
  float kacc[FCH], cacc[FCH];
  #pragma unroll
  for(int i=0;i<FCH;i++){ kacc[i]=0.f; cacc[i]=0.f; }
  float mymax = -3.4e38f;
  for(int tt=0; tt<4; tt++){
    int tc = tq*4 + tt;
    int t = lane*16 + tc;
    const float4* xp = (const float4*)(kfa + ((size_t)head*T_T + t)*D_H);
    float4 xr[16];
    #pragma unroll
    for(int kk=0;kk<16;kk++) xr[kk] = xp[kk];
    float dg = 0.f;
    #pragma unroll
    for(int kk=0;kk<16;kk++){ float4 x = xr[kk];
      dg += x.x*x.x + x.y*x.y + x.z*x.z + x.w*x.w; }
    dg *= DIAG_C;
    float cmul = ((tc < 8) && (mask[n*T_T + t] > -1.0f)) ? 1.f : 0.f;
    for(int fi=0; fi<FCH; fi++){
      const float4* pr = (const float4*)(pm + (size_t)(f0+fi)*D_H);
      float s0=0,s1=0,s2=0,s3=0;
      #pragma unroll
      for(int kk=0;kk<16;kk++){ float4 w4 = pr[kk];
        s0+=xr[kk].x*w4.x; s1+=xr[kk].y*w4.y; s2+=xr[kk].z*w4.z; s3+=xr[kk].w*w4.w; }
      float dd = DN_C*((s0+s1)+(s2+s3));
      mymax = fmaxf(mymax, dd);
      float e = expf(dd - dg);
      kacc[fi] += e;
      cacc[fi] += e*cmul;
    }
  }
  #pragma unroll
  for(int fi=0;fi<FCH;fi++){
    float s = waveSum(kacc[fi]);
    if(lane==0) kred[tq][fi] = s;
  }
  mymax = waveMax(mymax);
  if(lane==0) mred[tq]=mymax;
  if(tq==0){
    #pragma unroll
    for(int fi=0;fi<FCH;fi++) cred[fi][lane] = cacc[fi];
  }
  __syncthreads();
  if(tq==1){
    #pragma unroll
    for(int fi=0;fi<FCH;fi++) cred[fi][lane] += cacc[fi];
  }
  __syncthreads();
  for(int i=threadIdx.x; i<FCH*64; i+=256){
    int fi=i>>6, d=i&63;
    ctxraw[((size_t)head*F_F + f0+fi)*64 + d] = cred[fi][d];
  }
  if(threadIdx.x < FCH)
    ksumP[head*F_F + f0 + threadIdx.x] =
      kred[0][threadIdx.x]+kred[1][threadIdx.x]+kred[2][threadIdx.x]+kred[3][threadIdx.x];
  if(threadIdx.x==0)
    mfP[head*NCH+fc] = fmaxf(fmaxf(mred[0],mred[1]),fmaxf(mred[2],mred[3]));
}

// ---------------- Kernel B2: per-head fixup -------------------------------
__global__ __launch_bounds__(256) void fixup_kern(
    const float* __restrict__ mfP, const float* __restrict__ ksumP,
    const float* __restrict__ ctxraw, const float* __restrict__ mask,
    float* __restrict__ ctx, float* __restrict__ ksum,
    float* __restrict__ ksum_tot, float* __restrict__ ctx_tot){
  int head = blockIdx.x; int n = head/H_H;
  __shared__ float segc[64];
  __shared__ float part[4][64];
  __shared__ float kpart[4];
  float m_head = mfP[head*NCH];
  for(int i=1;i<NCH;i++) m_head = fmaxf(m_head, mfP[head*NCH+i]);
  float e_mh = expf(-m_head);
  if(threadIdx.x < 64){
    int d = threadIdx.x; float c=0.f;
    for(int i=0;i<8;i++) c += (mask[n*T_T + 16*d + i] > -1.0f) ? 1.f : 0.f;
    segc[d] = c;
  }
  __syncthreads();
  int g = threadIdx.x>>6, d = threadIdx.x&63;
  float ct = 0.f, kt = 0.f;
  for(int f=g; f<F_F; f+=4){
    float craw = ctxraw[((size_t)head*F_F+f)*64 + d];
    float cf = RATIO_C*(craw*e_mh + EPS_C*segc[d]);
    ctx[((size_t)head*F_F+f)*64 + d] = cf;
    ct += cf;
    if(d==0){
      float kf = RATIO_C*(ksumP[head*F_F+f]*e_mh + EPS_C*(float)T_T);
      ksum[head*F_F+f] = kf;
      kt += kf;
    }
  }
  part[g][d] = ct;
  if(d==0) kpart[g] = kt;
  __syncthreads();
  if(threadIdx.x < 64)
    ctx_tot[head*64+threadIdx.x] =
      part[0][threadIdx.x]+part[1][threadIdx.x]+part[2][threadIdx.x]+part[3][threadIdx.x];
  if(threadIdx.x==0) ksum_tot[head] = kpart[0]+kpart[1]+kpart[2]+kpart[3];
}

// ---------------- Kernel C v4: query features + pcl (deferred max) --------
__global__ __launch_bounds__(256) void qfeat_kern(
    const float* __restrict__ qfa, const float* __restrict__ pm,
    const float* __restrict__ ctx, const float* __restrict__ ksum,
    const float* __restrict__ ksum_tot, const float* __restrict__ ctx_tot,
    float* __restrict__ pcl){
  int head = blockIdx.x, tc = blockIdx.y;   // grid (48,16), 256 threads
  int rl = threadIdx.x >> 2, fs = threadIdx.x & 3;
  int t = tc*64 + rl;
  __shared__ float pms[56*68];
  __shared__ float ctxs[56*68];
  __shared__ float ksums[56];
  const float* xp = qfa + ((size_t)head*T_T + t)*D_H;
  float4 xr[16];
  #pragma unroll
  for(int kk=0;kk<16;kk++) xr[kk] = ((const float4*)xp)[kk];
  float diag = 0.f;
  #pragma unroll
  for(int kk=0;kk<16;kk++)
    diag += xr[kk].x*xr[kk].x + xr[kk].y*xr[kk].y + xr[kk].z*xr[kk].z + xr[kk].w*xr[kk].w;
  diag *= DIAG_C;
  float m_run = -3.4e38f, m_acc = 0.f, S = 0.f;
  bool first = true;
  float4 acc[16];
  #pragma unroll
  for(int kk=0;kk<16;kk++) acc[kk] = make_float4(0.f,0.f,0.f,0.f);
  for(int c=0;c<5;c++){
    int f0 = c*56, CF = min(56, F_F-f0);
    __syncthreads();
    for(int i=threadIdx.x;i<CF*16;i+=256){
      int fl=i>>4, d4=i&15;
      ((float4*)(pms+fl*68))[d4]  = ((const float4*)(pm+(size_t)(f0+fl)*64))[d4];
      ((float4*)(ctxs+fl*68))[d4] = ((const float4*)(ctx+((size_t)head*F_F+f0+fl)*64))[d4];
    }
    for(int i=threadIdx.x;i<CF;i+=256) ksums[i]=ksum[head*F_F+f0+i];
    __syncthreads();
    int nj = (CF - fs + 3)>>2;
    for(int j=0;j<nj;j++){
      int fl = fs+4*j;
      const float4* pr = (const float4*)(pms + fl*68);
      float s0=0,s1=0,s2=0,s3=0;
      #pragma unroll
      for(int kk=0;kk<16;kk++){ float4 w4 = pr[kk];
        s0+=xr[kk].x*w4.x; s1+=xr[kk].y*w4.y; s2+=xr[kk].z*w4.z; s3+=xr[kk].w*w4.w; }
      float dd = DN_C*((s0+s1)+(s2+s3));
      if(first){ m_acc = dd; first = false; }
      m_run = fmaxf(m_run, dd);
      float e = expf(dd - diag - m_acc);
      S += e * ksums[fl];
      const float4* cr = (const float4*)(ctxs + fl*68);
      #pragma unroll
      for(int kk=0;kk<16;kk++){ float4 c4=cr[kk];
        acc[kk].x+=e*c4.x; acc[kk].y+=e*c4.y; acc[kk].z+=e*c4.z; acc[kk].w+=e*c4.w; }
    }
  }
  {
    float fac = expf(m_acc - m_run);
    S *= fac;
    #pragma unroll
    for(int kk=0;kk<16;kk++){
      acc[kk].x*=fac; acc[kk].y*=fac; acc[kk].z*=fac; acc[kk].w*=fac;
    }
  }
  for(int st=1; st<=2; st<<=1){
    float mo = __shfl_xor(m_run, st, 64);
    float mc = fmaxf(m_run, mo);
    float fac = expf(m_run - mc);
    S *= fac;
    S += __shfl_xor(S, st, 64);
    #pragma unroll
    for(int kk=0;kk<16;kk++){
      acc[kk].x*=fac; acc[kk].y*=fac; acc[kk].z*=fac; acc[kk].w*=fac;
    }
    #pragma unroll
    for(int kk=0;kk<16;kk++){
      acc[kk].x += __shfl_xor(acc[kk].x,st,64);
      acc[kk].y += __shfl_xor(acc[kk].y,st,64);
      acc[kk].z += __shfl_xor(acc[kk].z,st,64);
      acc[kk].w += __shfl_xor(acc[kk].w,st,64);
    }
    m_run = mc;
  }
  float den = S + EPS_C * ksum_tot[head];
  float dinv = 1.0f/den;
  float4 w0,w1,w2,w3;
  if(fs==0){ w0=acc[0]; w1=acc[1]; w2=acc[2]; w3=acc[3]; }
  else if(fs==1){ w0=acc[4]; w1=acc[5]; w2=acc[6]; w3=acc[7]; }
  else if(fs==2){ w0=acc[8]; w1=acc[9]; w2=acc[10]; w3=acc[11]; }
  else { w0=acc[12]; w1=acc[13]; w2=acc[14]; w3=acc[15]; }
  const float4* ctp = ((const float4*)(ctx_tot + head*64)) + fs*4;
  float4 c0=ctp[0], c1=ctp[1], c2=ctp[2], c3=ctp[3];
  float4* po = (float4*)(pcl + ((size_t)head*T_T + t)*D_H) + fs*4;
  po[0] = make_float4((w0.x+EPS_C*c0.x)*dinv,(w0.y+EPS_C*c0.y)*dinv,(w0.z+EPS_C*c0.z)*dinv,(w0.w+EPS_C*c0.w)*dinv);
  po[1] = make_float4((w1.x+EPS_C*c1.x)*dinv,(w1.y+EPS_C*c1.y)*dinv,(w1.z+EPS_C*c1.z)*dinv,(w1.w+EPS_C*c1.w)*dinv);
  po[2] = make_float4((w2.x+EPS_C*c2.x)*dinv,(w2.y+EPS_C*c2.y)*dinv,(w2.z+EPS_C*c2.z)*dinv,(w2.w+EPS_C*c2.w)*dinv);
  po[3] = make_float4((w3.x+EPS_C*c3.x)*dinv,(w3.y+EPS_C*c3.y)*dinv,(w3.z+EPS_C*c3.z)*dinv,(w3.w+EPS_C*c3.w)*dinv);
}

// ---------------- Kernel D: MLP + LN + GELU + score + softmax -------------
#define FMA4(A,s,W) {A.x+=(s)*W.x; A.y+=(s)*W.y; A.z+=(s)*W.z; A.w+=(s)*W.w;}
__global__ __launch_bounds__(256) void mlp_kern(
    const float* __restrict__ pcl, const float* __restrict__ v,
    const float* __restrict__ mask,
    const float* __restrict__ encw, const float* __restrict__ encb,
    const float* __restrict__ lng, const float* __restrict__ lnb,
    const float* __restrict__ decw, const float* __restrict__ decb,
    float* __restrict__ probsout, float* __restrict__ scoreout){
  int head = blockIdx.x, tblk = blockIdx.y;   // grid (48,32)
  int t0 = tblk*32;
  int n = head / H_H;
  __shared__ float xs[32*132];
  __shared__ float wts[32*132];
  __shared__ float h1s[32*132];
  int colT = threadIdx.x & 15, rowT = threadIdx.x >> 4;
  int r0 = rowT, r1 = rowT + 16;
  const float* pclrow = pcl + ((size_t)head*T_T + t0)*D_H;
  const float* vrow   = v   + ((size_t)head*T_T + t0)*D_H;
  for(int i=threadIdx.x;i<512;i+=256){
    int r=i>>4, q=i&15;
    ((float4*)(xs + r*132))[q]      = ((const float4*)(pclrow + r*64))[q];
    ((float4*)(xs + r*132 + 64))[q] = ((const float4*)(vrow   + r*64))[q];
  }
  float4 bias0 = ((const float4*)encb)[colT];
  float4 bias1 = ((const float4*)encb)[colT+16];
  float4 A0=bias0, A1=bias1, B0=bias0, B1=bias1;
  for(int kc=0;kc<4;kc++){
    __syncthreads();
    for(int i=threadIdx.x;i<1024;i+=256){
      int k=i>>5, q=i&31;
      ((float4*)(wts + k*132))[q] = ((const float4*)(encw + (size_t)(kc*32+k)*128))[q];
    }
    __syncthreads();
    #pragma unroll
    for(int kq=0;kq<8;kq++){
      float4 x0 = ((const float4*)(xs + r0*132 + kc*32))[kq];
      float4 x1 = ((const float4*)(xs + r1*132 + kc*32))[kq];
      #pragma unroll
      for(int kk=0;kk<4;kk++){
        const float* wrow = wts + (kq*4+kk)*132;
        float4 wa = ((const float4*)wrow)[colT];
        float4 wb = ((const float4*)wrow)[colT+16];
        float xv0 = (kk==0)?x0.x:(kk==1)?x0.y:(kk==2)?x0.z:x0.w;
        float xv1 = (kk==0)?x1.x:(kk==1)?x1.y:(kk==2)?x1.z:x1.w;
        FMA4(A0,xv0,wa); FMA4(A1,xv0,wb);
        FMA4(B0,xv1,wa); FMA4(B1,xv1,wb);
      }
    }
  }
  float4 lg0 = ((const float4*)lng)[colT], lg1 = ((const float4*)lng)[colT+16];
  float4 lb0 = ((const float4*)lnb)[colT], lb1 = ((const float4*)lnb)[colT+16];
  float s0 = A0.x+A0.y+A0.z+A0.w + A1.x+A1.y+A1.z+A1.w;
  float s1 = B0.x+B0.y+B0.z+B0.w + B1.x+B1.y+B1.z+B1.w;
  for(int o=1;o<16;o<<=1){ s0 += __shfl_xor(s0,o,64); s1 += __shfl_xor(s1,o,64); }
  float mu0 = s0*(1.0f/128.0f), mu1 = s1*(1.0f/128.0f);
  float v0=0.f, v1=0.f;
  { float d;
    d=A0.x-mu0; v0+=d*d; d=A0.y-mu0; v0+=d*d; d=A0.z-mu0; v0+=d*d; d=A0.w-mu0; v0+=d*d;
    d=A1.x-mu0; v0+=d*d; d=A1.y-mu0; v0+=d*d; d=A1.z-mu0; v0+=d*d; d=A1.w-mu0; v0+=d*d;
    d=B0.x-mu1; v1+=d*d; d=B0.y-mu1; v1+=d*d; d=B0.z-mu1; v1+=d*d; d=B0.w-mu1; v1+=d*d;
    d=B1.x-mu1; v1+=d*d; d=B1.y-mu1; v1+=d*d; d=B1.z-mu1; v1+=d*d; d=B1.w-mu1; v1+=d*d; }
  for(int o=1;o<16;o<<=1){ v0 += __shfl_xor(v0,o,64); v1 += __shfl_xor(v1,o,64); }
  float den0 = sqrtf(v0*(1.0f/128.0f)+1e-5f);
  float den1 = sqrtf(v1*(1.0f/128.0f)+1e-5f);
  #define GELU(x) ((x)*0.5f*(1.0f+erff((x)*0.70710678118654752f)))
  #define LNG(a,mu,dn,g,b) GELU(((a)-(mu))/(dn)*(g)+(b))
  float4 H;
  H.x=LNG(A0.x,mu0,den0,lg0.x,lb0.x); H.y=LNG(A0.y,mu0,den0,lg0.y,lb0.y);
  H.z=LNG(A0.z,mu0,den0,lg0.z,lb0.z); H.w=LNG(A0.w,mu0,den0,lg0.w,lb0.w);
  ((float4*)(h1s + r0*132))[colT] = H;
  H.x=LNG(A1.x,mu0,den0,lg1.x,lb1.x); H.y=LNG(A1.y,mu0,den0,lg1.y,lb1.y);
  H.z=LNG(A1.z,mu0,den0,lg1.z,lb1.z); H.w=LNG(A1.w,mu0,den0,lg1.w,lb1.w);
  ((float4*)(h1s + r0*132))[colT+16] = H;
  H.x=LNG(B0.x,mu1,den1,lg0.x,lb0.x); H.y=LNG(B0.y,mu1,den1,lg0.y,lb0.y);
  H.z=LNG(B0.z,mu1,den1,lg0.z,lb0.z); H.w=LNG(B0.w,mu1,den1,lg0.w,lb0.w);
  ((float4*)(h1s + r1*132))[colT] = H;
  H.x=LNG(B1.x,mu1,den1,lg1.x,lb1.x); H.y=LNG(B1.y,mu1,den1,lg1.y,lb1.y);
  H.z=LNG(B1.z,mu1,den1,lg1.z,lb1.z); H.w=LNG(B1.w,mu1,den1,lg1.w,lb1.w);
  ((float4*)(h1s + r1*132))[colT+16] = H;
  bias0 = ((const float4*)decb)[colT];
  bias1 = ((const float4*)decb)[colT+16];
  A0=bias0; A1=bias1; B0=bias0; B1=bias1;
  for(int kc=0;kc<4;kc++){
    __syncthreads();
    for(int i=threadIdx.x;i<1024;i+=256){
      int k=i>>5, q=i&31;
      ((float4*)(wts + k*132))[q] = ((const float4*)(decw + (size_t)(kc*32+k)*128))[q];
    }
    __syncthreads();
    #pragma unroll
    for(int kq=0;kq<8;kq++){
      float4 x0 = ((const float4*)(h1s + r0*132 + kc*32))[kq];
      float4 x1 = ((const float4*)(h1s + r1*132 + kc*32))[kq];
      #pragma unroll
      for(int kk=0;kk<4;kk++){
        const float* wrow = wts + (kq*4+kk)*132;
        float4 wa = ((const float4*)wrow)[colT];
        float4 wb = ((const float4*)wrow)[colT+16];
        float xv0 = (kk==0)?x0.x:(kk==1)?x0.y:(kk==2)?x0.z:x0.w;
        float xv1 = (kk==0)?x1.x:(kk==1)?x1.y:(kk==2)?x1.z:x1.w;
        FMA4(A0,xv0,wa); FMA4(A1,xv0,wb);
        FMA4(B0,xv1,wa); FMA4(B1,xv1,wb);
      }
    }
  }
  const float* mrow = mask + n*T_T;
  int c0 = colT*4, c1 = colT*4 + 64;
  float rm0[4], rm1[4];
  #pragma unroll
  for(int i=0;i<4;i++){ rm0[i]=mrow[(c0+i)*8]; rm1[i]=mrow[(c1+i)*8]; }
  float sA[8], sB[8];
  sA[0]=(rm0[0]<-1.f)?-10000.f:A0.x; sA[1]=(rm0[1]<-1.f)?-10000.f:A0.y;
  sA[2]=(rm0[2]<-1.f)?-10000.f:A0.z; sA[3]=(rm0[3]<-1.f)?-10000.f:A0.w;
  sA[4]=(rm1[0]<-1.f)?-10000.f:A1.x; sA[5]=(rm1[1]<-1.f)?-10000.f:A1.y;
  sA[6]=(rm1[2]<-1.f)?-10000.f:A1.z; sA[7]=(rm1[3]<-1.f)?-10000.f:A1.w;
  sB[0]=(rm0[0]<-1.f)?-10000.f:B0.x; sB[1]=(rm0[1]<-1.f)?-10000.f:B0.y;
  sB[2]=(rm0[2]<-1.f)?-10000.f:B0.z; sB[3]=(rm0[3]<-1.f)?-10000.f:B0.w;
  sB[4]=(rm1[0]<-1.f)?-10000.f:B1.x; sB[5]=(rm1[1]<-1.f)?-10000.f:B1.y;
  sB[6]=(rm1[2]<-1.f)?-10000.f:B1.z; sB[7]=(rm1[3]<-1.f)?-10000.f:B1.w;
  float mx0=sA[0], mx1=sB[0];
  #pragma unroll
  for(int i=1;i<8;i++){ mx0=fmaxf(mx0,sA[i]); mx1=fmaxf(mx1,sB[i]); }
  for(int o=1;o<16;o<<=1){ mx0=fmaxf(mx0,__shfl_xor(mx0,o,64)); mx1=fmaxf(mx1,__shfl_xor(mx1,o,64)); }
  float Z0=0.f, Z1=0.f;
  #pragma unroll
  for(int i=0;i<8;i++){ sA[i]=expf(sA[i]-mx0); Z0+=sA[i]; sB[i]=expf(sB[i]-mx1); Z1+=sB[i]; }
  for(int o=1;o<16;o<<=1){ Z0+=__shfl_xor(Z0,o,64); Z1+=__shfl_xor(Z1,o,64); }
  float zi0=1.0f/Z0, zi1=1.0f/Z1;
  size_t rb0 = ((size_t)head*T_T + t0 + r0)*TM_;
  size_t rb1 = ((size_t)head*T_T + t0 + r1)*TM_;
  ((float4*)(probsout+rb0))[colT]    = make_float4(sA[0]*zi0,sA[1]*zi0,sA[2]*zi0,sA[3]*zi0);
  ((float4*)(probsout+rb0))[colT+16] = make_float4(sA[4]*zi0,sA[5]*zi0,sA[6]*zi0,sA[7]*zi0);
  ((float4*)(probsout+rb1))[colT]    = make_float4(sB[0]*zi1,sB[1]*zi1,sB[2]*zi1,sB[3]*zi1);
  ((float4*)(probsout+rb1))[colT+16] = make_float4(sB[4]*zi1,sB[5]*zi1,sB[6]*zi1,sB[7]*zi1);
  ((float4*)(scoreout+rb0))[colT]    = A0;
  ((float4*)(scoreout+rb0))[colT+16] = A1;
  ((float4*)(scoreout+rb1))[colT]    = B0;
  ((float4*)(scoreout+rb1))[colT+16] = B1;
}

// ---------------- Kernel E v3: per-row KL + MSE, register-resident --------
__global__ __launch_bounds__(256) void loss_kern(
    const float* __restrict__ truth, const float* __restrict__ mask,
    const float* __restrict__ score, float* __restrict__ klrow,
    float* __restrict__ mserow){
  int row = blockIdx.x;               // head*1024 + t
  int n = row / (H_H*T_T);
  int t = threadIdx.x;
  int lane = t & 63, tq = t >> 6;
  __shared__ float sc[128];
  __shared__ float red[8];
  float4 av  = ((const float4*)(truth + (size_t)row*T_T))[t];
  float4 mkv = ((const float4*)(mask + (size_t)n*T_T))[t];
  if(t < 128) sc[t] = score[(size_t)row*TM_ + t];
  __syncthreads();
  float scv = sc[t>>1];
  float ma = fmaxf(fmaxf(av.x+mkv.x, av.y+mkv.y), fmaxf(av.z+mkv.z, av.w+mkv.w));
  float ms = scv + fmaxf(fmaxf(mkv.x, mkv.y), fmaxf(mkv.z, mkv.w));
  for(int o=32;o;o>>=1){ ma=fmaxf(ma,__shfl_xor(ma,o,64)); ms=fmaxf(ms,__shfl_xor(ms,o,64)); }
  if(lane==0){ red[tq]=ma; red[4+tq]=ms; }
  __syncthreads();
  ma = fmaxf(fmaxf(red[0],red[1]),fmaxf(red[2],red[3]));
  ms = fmaxf(fmaxf(red[4],red[5]),fmaxf(red[6],red[7]));
  __syncthreads();
  float e0=__expf(av.x+mkv.x-ma), e1=__expf(av.y+mkv.y-ma),
        e2=__expf(av.z+mkv.z-ma), e3=__expf(av.w+mkv.w-ma);
  float Za = (e0+e1)+(e2+e3);
  float Zs = (__expf(scv+mkv.x-ms)+__expf(scv+mkv.y-ms))
           + (__expf(scv+mkv.z-ms)+__expf(scv+mkv.w-ms));
  for(int o=32;o;o>>=1){ Za+=__shfl_xor(Za,o,64); Zs+=__shfl_xor(Zs,o,64); }
  if(lane==0){ red[tq]=Za; red[4+tq]=Zs; }
  __syncthreads();
  Za = (red[0]+red[1])+(red[2]+red[3]);
  Zs = (red[4]+red[5])+(red[6]+red[7]);
  __syncthreads();
  float lZs = __logf(Zs), lZa = __logf(Za);
  float invZa = 1.0f/Za;
  float kl=0.f, mse=0.f;
  #define LKL(AJ,MKJ,EJ) { \
    if((MKJ) > -1.0f){ \
      float pt = (EJ)*invZa; \
      float logpt = (pt >= 1e-12f) ? ((AJ)+(MKJ)-ma-lZa) : -27.631021116f; \
      float logp = (scv+(MKJ)-ms) - lZs; \
      kl += pt*(logpt-logp); } \
    float sv = ((MKJ) < -1.0f)?0.f:scv; \
    float avv = ((MKJ) < -1.0f)?0.f:(AJ); \
    float dd = sv-avv; mse += dd*dd; }
  LKL(av.x,mkv.x,e0) LKL(av.y,mkv.y,e1) LKL(av.z,mkv.z,e2) LKL(av.w,mkv.w,e3)
  #undef LKL
  for(int o=32;o;o>>=1){ kl+=__shfl_xor(kl,o,64); mse+=__shfl_xor(mse,o,64); }
  if(lane==0){ red[tq]=kl; red[4+tq]=mse; }
  __syncthreads();
  if(t==0){
    klrow[row]  = (red[0]+red[1])+(red[2]+red[3]);
    mserow[row] = (red[4]+red[5])+(red[6]+red[7]);
  }
}

// ---------------- Kernel F: final loss ------------------------------------
__global__ __launch_bounds__(256) void finloss_kern(
    const float* __restrict__ klrow, const float* __restrict__ mserow,
    const float* __restrict__ mask, float* __restrict__ out0){
  __shared__ double reds[256];
  double kls=0, mses=0;
  for(int i=threadIdx.x;i<N_H*T_T;i+=256){ kls+=(double)klrow[i]; mses+=(double)mserow[i]; }
  double vcnt=0;
  for(int i=threadIdx.x;i<N_B*T_T;i+=256) if(mask[i] > -1.0f) vcnt+=1.0;
  reds[threadIdx.x]=kls; __syncthreads();
  for(int o=128;o;o>>=1){ if(threadIdx.x<o) reds[threadIdx.x]+=reds[threadIdx.x+o]; __syncthreads(); }
  double klsum = reds[0]; __syncthreads();
  reds[threadIdx.x]=mses; __syncthreads();
  for(int o=128;o;o>>=1){ if(threadIdx.x<o) reds[threadIdx.x]+=reds[threadIdx.x+o]; __syncthreads(); }
  double msesum = reds[0]; __syncthreads();
  reds[threadIdx.x]=vcnt; __syncthreads();
  for(int o=128;o;o>>=1){ if(threadIdx.x<o) reds[threadIdx.x]+=reds[threadIdx.x+o]; __syncthreads(); }
  if(threadIdx.x==0){
    double denom = reds[0] * (double)(H_H*T_T);
    double loss = klsum/denom*0.25 + msesum/((double)N_B*H_H*T_T*T_T);
    out0[0]=(float)loss;
  }
}

// ---------------- Top-k pipeline (R10 known-good: 4 x 8-bit, LDS atomics) --
__global__ void topk_init(unsigned* __restrict__ hist, unsigned* __restrict__ state,
                          unsigned* __restrict__ tiecnt){
  int i = blockIdx.x*256+threadIdx.x;
  if(i < 4*256) hist[i]=0;
  if(i < 4){ state[i*4+0]=0u; state[i*4+1]=KSEL; state[i*4+2]=0u; tiecnt[i]=0u; }
}

__global__ __launch_bounds__(256) void topk_hist(
    const float* __restrict__ probs, const float* __restrict__ mask,
    const unsigned* __restrict__ state, unsigned* __restrict__ hist, int level){
  __shared__ unsigned lh[4*256];
  for(int i=threadIdx.x;i<1024;i+=256) lh[i]=0;
  __syncthreads();
  unsigned pmask = (level==0)?0u:(0xFFFFFFFFu << (32-8*level));
  unsigned pref[4];
  for(int b=0;b<4;b++) pref[b]=state[b*4+0] & pmask;
  int shift = 24-8*level;
  size_t total = (size_t)N_B*PER_BATCH;
  for(size_t idx = (size_t)blockIdx.x*256+threadIdx.x; idx < total; idx += (size_t)gridDim.x*256){
    int b = (int)(idx / PER_BATCH);
    unsigned r = (unsigned)(idx - (size_t)b*PER_BATCH);
    int t = (int)((r>>7)&1023u);
    float val = probs[idx];
    if(!(mask[b*T_T+t] > -1.0f)) val = 0.0f;
    unsigned u = __float_as_uint(val);
    if((u & pmask) == pref[b]) atomicAdd(&lh[b*256+((u>>shift)&255u)],1u);
  }
  __syncthreads();
  for(int i=threadIdx.x;i<1024;i+=256){
    unsigned c = lh[i];
    if(c) atomicAdd(&hist[i], c);
  }
}

__global__ void topk_scan(unsigned* __restrict__ hist, unsigned* __restrict__ state, int level){
  int b = blockIdx.x;
  if(threadIdx.x==0){
    const unsigned* h = hist + b*256;
    unsigned remk = state[b*4+1];
    unsigned cum = 0; int sel=0;
    for(int bin=255; bin>=0; bin--){
      unsigned c = h[bin];
      if(remk <= cum + c){ sel=bin; break; }
      cum += c;
    }
    state[b*4+0] |= ((unsigned)sel) << (24-8*level);
    state[b*4+1] = remk - cum;
    state[b*4+2] += cum;
  }
  __syncthreads();
  for(int i=threadIdx.x;i<256;i+=blockDim.x) hist[b*256+i]=0;
}

__global__ __launch_bounds__(256) void topk_write(
    const float* __restrict__ probs, const float* __restrict__ mask,
    const unsigned* __restrict__ state, float* __restrict__ pam,
    unsigned* __restrict__ ties, unsigned* __restrict__ tiecnt){
  unsigned thr[4];
  for(int b=0;b<4;b++) thr[b]=state[b*4+0];
  size_t total=(size_t)N_B*PER_BATCH;
  for(size_t idx=(size_t)blockIdx.x*256+threadIdx.x; idx<total; idx += (size_t)gridDim.x*256){
    int b = (int)(idx / PER_BATCH);
    unsigned r = (unsigned)(idx - (size_t)b*PER_BATCH);
    int t = (int)((r>>7)&1023u);
    float val = probs[idx];
    if(!(mask[b*T_T+t] > -1.0f)) val=0.0f;
    unsigned u=__float_as_uint(val);
    float o = -10000.0f;
    if(u > thr[b]) o = 0.0f;
    else if(u == thr[b]){
      unsigned pos = atomicAdd(&tiecnt[b],1u);
      if(pos < 65536u) ties[(size_t)b*65536+pos]=r;
    }
    pam[idx]=o;
  }
}

__global__ __launch_bounds__(256) void topk_ties(
    const unsigned* __restrict__ state, const unsigned* __restrict__ ties,
    const unsigned* __restrict__ tiecnt, float* __restrict__ pam){
  int b = blockIdx.x;
  unsigned needed = state[b*4+1];
  unsigned nt = min(tiecnt[b], 65536u);
  __shared__ unsigned redu[256];
  __shared__ unsigned lohi[2];
  if(threadIdx.x==0){ lohi[0]=0u; lohi[1]=PER_BATCH; }
  __syncthreads();
  if(needed == 0 || nt == 0) return;
  while(true){
    __syncthreads();
    unsigned lo=lohi[0], hi=lohi[1];
    if(hi-lo<=1u) break;
    unsigned mid=(lo+hi)>>1;
    unsigned c=0;
    for(unsigned i=threadIdx.x;i<nt;i+=256) c += (ties[(size_t)b*65536+i] < mid)?1u:0u;
    redu[threadIdx.x]=c; __syncthreads();
    for(int o=128;o;o>>=1){ if(threadIdx.x<o) redu[threadIdx.x]+=redu[threadIdx.x+o]; __syncthreads(); }
    if(threadIdx.x==0){ if(redu[0]>=needed) lohi[1]=mid; else lohi[0]=mid; }
  }
  __syncthreads();
  unsigned X=lohi[1];
  for(unsigned i=threadIdx.x;i<nt;i+=256){
    unsigned r=ties[(size_t)b*65536+i];
    if(r < X) pam[(size_t)b*PER_BATCH + r]=0.0f;
  }
}

// ---------------- launcher ------------------------------------------------
extern "C" void kernel_launch(void* const* d_in, const int* in_sizes, int n_in,
                              void* d_out, int out_size, void* d_ws, size_t ws_size,
                              hipStream_t stream) {
  const float* v     = (const float*)d_in[2];
  const float* qfa   = (const float*)d_in[3];
  const float* kfa   = (const float*)d_in[4];
  const float* mask  = (const float*)d_in[8];
  const float* truth = (const float*)d_in[9];
  const float* pm    = (const float*)d_in[11];
  const float* encw  = (const float*)d_in[12];
  const float* encb  = (const float*)d_in[13];
  const float* lng   = (const float*)d_in[14];
  const float* lnb   = (const float*)d_in[15];
  const float* decw  = (const float*)d_in[16];
  const float* decb  = (const float*)d_in[17];
  float* out = (float*)d_out;
  float* ws  = (float*)d_ws;

  float* ctx     = ws;                              // 817152
  float* ksum    = ctx + (size_t)N_H*F_F*64;        // 12768
  float* klrow   = ksum + N_H*F_F;                  // 49152
  float* mserow  = klrow + N_H*T_T;                 // 49152
  unsigned* hist   = (unsigned*)(mserow + N_H*T_T); // 1024
  unsigned* state  = hist + 1024;                   // 16
  unsigned* tiecnt = state + 16;                    // 4 (+pad)
  unsigned* ties   = tiecnt + 12;                   // 4*65536
  float* ctxraw  = (float*)(ties + (size_t)4*65536);// 817152
  float* ksumP   = ctxraw + (size_t)N_H*F_F*64;     // 12768
  float* mfP     = ksumP + N_H*F_F;                 // 912 (+pad)
  float* ksum_tot= mfP + 1024;                      // 48
  float* ctx_tot = ksum_tot + 48;                   // 3072

  float* pcl   = out + 1;
  float* probs = pcl + (size_t)N_H*T_T*D_H;
  float* pam   = probs + (size_t)N_H*T_T*TM_;

  keyfeat_kern<<<dim3(N_H,NCH),256,0,stream>>>(kfa, pm, mask, ctxraw, ksumP, mfP);
  fixup_kern<<<N_H,256,0,stream>>>(mfP, ksumP, ctxraw, mask, ctx, ksum, ksum_tot, ctx_tot);
  qfeat_kern<<<dim3(N_H,16),256,0,stream>>>(qfa, pm, ctx, ksum, ksum_tot, ctx_tot, pcl);
  mlp_kern<<<dim3(N_H,32),256,0,stream>>>(pcl, v, mask, encw, encb, lng, lnb,
                                          decw, decb, probs, pam /*score*/);
  loss_kern<<<N_H*T_T,256,0,stream>>>(truth, mask, pam /*score*/, klrow, mserow);
  finloss_kern<<<1,256,0,stream>>>(klrow, mserow, mask, out);
  topk_init<<<4,256,0,stream>>>(hist, state, tiecnt);
  for(int lvl=0;lvl<4;lvl++){
    topk_hist<<<2048,256,0,stream>>>(probs, mask, state, hist, lvl);
    topk_scan<<<4,64,0,stream>>>(hist, state, lvl);
  }
  topk_write<<<2048,256,0,stream>>>(probs, mask, state, pam, ties, tiecnt);
  topk_ties<<<4,256,0,stream>>>(state, ties, tiecnt, pam);
}

// Round 14
// 557.751 us; speedup vs baseline: 2.5733x; 1.0412x over previous
//
#include <hip/hip_runtime.h>
#include <hip/hip_bf16.h>
#include <math.h>

#define N_B 4
#define H_H 12
#define T_T 1024
#define D_H 64
#define F_F 266
#define N_H 48          // N_B*H_H
#define TM_ 128
#define KSEL 98304u     // kk*T*H = 8*1024*12
#define PER_BATCH 1572864  // H*T*TM
#define FCH 14
#define NCH 19          // 19*14 = 266

static __device__ __forceinline__ float waveSum(float v){
  for(int o=32;o;o>>=1) v += __shfl_xor(v,o,64);
  return v;
}
static __device__ __forceinline__ float waveMax(float v){
  for(int o=32;o;o>>=1) v = fmaxf(v,__shfl_xor(v,o,64));
  return v;
}

#define DN_C 0.35355339059327373f   // 64^-0.25 = 2^-1.5
#define DIAG_C 0.0625f              // 0.5 * 64^-0.5
#define RATIO_C 0.06131393394849658f // 266^-0.5
#define EPS_C 1e-4f

// ---------------- Kernel B v4: key features, lane-owns-t-strided ----------
__global__ __launch_bounds__(256) void keyfeat_kern(
    const float* __restrict__ kfa, const float* __restrict__ pm,
    const float* __restrict__ mask,
    float* __restrict__ ctxraw, float* __restrict__ ksumP,
    float* __restrict__ mfP){
  int head = blockIdx.x, fc = blockIdx.y;
  int f0 = fc*FCH;
  int n = head / H_H;
  int lane = threadIdx.x & 63, tq = threadIdx.x >> 6;
  __shared__ float cred[FCH][64];
  __shared__ float kred[4][FCH];
  __shared__ float mred[4];
  float kacc[FCH], cacc[FCH];
  #pragma unroll
  for(int i=0;i<FCH;i++){ kacc[i]=0.f; cacc[i]=0.f; }
  float mymax = -3.4e38f;
  for(int tt=0; tt<4; tt++){
    int tc = tq*4 + tt;
    int t = lane*16 + tc;
    const float4* xp = (const float4*)(kfa + ((size_t)head*T_T + t)*D_H);
    float4 xr[16];
    #pragma unroll
    for(int kk=0;kk<16;kk++) xr[kk] = xp[kk];
    float dg = 0.f;
    #pragma unroll
    for(int kk=0;kk<16;kk++){ float4 x = xr[kk];
      dg += x.x*x.x + x.y*x.y + x.z*x.z + x.w*x.w; }
    dg *= DIAG_C;
    float cmul = ((tc < 8) && (mask[n*T_T + t] > -1.0f)) ? 1.f : 0.f;
    for(int fi=0; fi<FCH; fi++){
      const float4* pr = (const float4*)(pm + (size_t)(f0+fi)*D_H);
      float s0=0,s1=0,s2=0,s3=0;
      #pragma unroll
      for(int kk=0;kk<16;kk++){ float4 w4 = pr[kk];
        s0+=xr[kk].x*w4.x; s1+=xr[kk].y*w4.y; s2+=xr[kk].z*w4.z; s3+=xr[kk].w*w4.w; }
      float dd = DN_C*((s0+s1)+(s2+s3));
      mymax = fmaxf(mymax, dd);
      float e = expf(dd - dg);
      kacc[fi] += e;
      cacc[fi] += e*cmul;
    }
  }
  #pragma unroll
  for(int fi=0;fi<FCH;fi++){
    float s = waveSum(kacc[fi]);
    if(lane==0) kred[tq][fi] = s;
  }
  mymax = waveMax(mymax);
  if(lane==0) mred[tq]=mymax;
  if(tq==0){
    #pragma unroll
    for(int fi=0;fi<FCH;fi++) cred[fi][lane] = cacc[fi];
  }
  __syncthreads();
  if(tq==1){
    #pragma unroll
    for(int fi=0;fi<FCH;fi++) cred[fi][lane] += cacc[fi];
  }
  __syncthreads();
  for(int i=threadIdx.x; i<FCH*64; i+=256){
    int fi=i>>6, d=i&63;
    ctxraw[((size_t)head*F_F + f0+fi)*64 + d] = cred[fi][d];
  }
  if(threadIdx.x < FCH)
    ksumP[head*F_F + f0 + threadIdx.x] =
      kred[0][threadIdx.x]+kred[1][threadIdx.x]+kred[2][threadIdx.x]+kred[3][threadIdx.x];
  if(threadIdx.x==0)
    mfP[head*NCH+fc] = fmaxf(fmaxf(mred[0],mred[1]),fmaxf(mred[2],mred[3]));
}

// ---------------- Kernel B2: per-head fixup -------------------------------
__global__ __launch_bounds__(256) void fixup_kern(
    const float* __restrict__ mfP, const float* __restrict__ ksumP,
    const float* __restrict__ ctxraw, const float* __restrict__ mask,
    float* __restrict__ ctx, float* __restrict__ ksum,
    float* __restrict__ ksum_tot, float* __restrict__ ctx_tot){
  int head = blockIdx.x; int n = head/H_H;
  __shared__ float segc[64];
  __shared__ float part[4][64];
  __shared__ float kpart[4];
  float m_head = mfP[head*NCH];
  for(int i=1;i<NCH;i++) m_head = fmaxf(m_head, mfP[head*NCH+i]);
  float e_mh = expf(-m_head);
  if(threadIdx.x < 64){
    int d = threadIdx.x; float c=0.f;
    for(int i=0;i<8;i++) c += (mask[n*T_T + 16*d + i] > -1.0f) ? 1.f : 0.f;
    segc[d] = c;
  }
  __syncthreads();
  int g = threadIdx.x>>6, d = threadIdx.x&63;
  float ct = 0.f, kt = 0.f;
  for(int f=g; f<F_F; f+=4){
    float craw = ctxraw[((size_t)head*F_F+f)*64 + d];
    float cf = RATIO_C*(craw*e_mh + EPS_C*segc[d]);
    ctx[((size_t)head*F_F+f)*64 + d] = cf;
    ct += cf;
    if(d==0){
      float kf = RATIO_C*(ksumP[head*F_F+f]*e_mh + EPS_C*(float)T_T);
      ksum[head*F_F+f] = kf;
      kt += kf;
    }
  }
  part[g][d] = ct;
  if(d==0) kpart[g] = kt;
  __syncthreads();
  if(threadIdx.x < 64)
    ctx_tot[head*64+threadIdx.x] =
      part[0][threadIdx.x]+part[1][threadIdx.x]+part[2][threadIdx.x]+part[3][threadIdx.x];
  if(threadIdx.x==0) ksum_tot[head] = kpart[0]+kpart[1]+kpart[2]+kpart[3];
}

// ---------------- Kernel C v4: query features + pcl (deferred max) --------
__global__ __launch_bounds__(256) void qfeat_kern(
    const float* __restrict__ qfa, const float* __restrict__ pm,
    const float* __restrict__ ctx, const float* __restrict__ ksum,
    const float* __restrict__ ksum_tot, const float* __restrict__ ctx_tot,
    float* __restrict__ pcl){
  int head = blockIdx.x, tc = blockIdx.y;   // grid (48,16), 256 threads
  int rl = threadIdx.x >> 2, fs = threadIdx.x & 3;
  int t = tc*64 + rl;
  __shared__ float pms[56*68];
  __shared__ float ctxs[56*68];
  __shared__ float ksums[56];
  const float* xp = qfa + ((size_t)head*T_T + t)*D_H;
  float4 xr[16];
  #pragma unroll
  for(int kk=0;kk<16;kk++) xr[kk] = ((const float4*)xp)[kk];
  float diag = 0.f;
  #pragma unroll
  for(int kk=0;kk<16;kk++)
    diag += xr[kk].x*xr[kk].x + xr[kk].y*xr[kk].y + xr[kk].z*xr[kk].z + xr[kk].w*xr[kk].w;
  diag *= DIAG_C;
  float m_run = -3.4e38f, m_acc = 0.f, S = 0.f;
  bool first = true;
  float4 acc[16];
  #pragma unroll
  for(int kk=0;kk<16;kk++) acc[kk] = make_float4(0.f,0.f,0.f,0.f);
  for(int c=0;c<5;c++){
    int f0 = c*56, CF = min(56, F_F-f0);
    __syncthreads();
    for(int i=threadIdx.x;i<CF*16;i+=256){
      int fl=i>>4, d4=i&15;
      ((float4*)(pms+fl*68))[d4]  = ((const float4*)(pm+(size_t)(f0+fl)*64))[d4];
      ((float4*)(ctxs+fl*68))[d4] = ((const float4*)(ctx+((size_t)head*F_F+f0+fl)*64))[d4];
    }
    for(int i=threadIdx.x;i<CF;i+=256) ksums[i]=ksum[head*F_F+f0+i];
    __syncthreads();
    int nj = (CF - fs + 3)>>2;
    for(int j=0;j<nj;j++){
      int fl = fs+4*j;
      const float4* pr = (const float4*)(pms + fl*68);
      float s0=0,s1=0,s2=0,s3=0;
      #pragma unroll
      for(int kk=0;kk<16;kk++){ float4 w4 = pr[kk];
        s0+=xr[kk].x*w4.x; s1+=xr[kk].y*w4.y; s2+=xr[kk].z*w4.z; s3+=xr[kk].w*w4.w; }
      float dd = DN_C*((s0+s1)+(s2+s3));
      if(first){ m_acc = dd; first = false; }
      m_run = fmaxf(m_run, dd);
      float e = expf(dd - diag - m_acc);
      S += e * ksums[fl];
      const float4* cr = (const float4*)(ctxs + fl*68);
      #pragma unroll
      for(int kk=0;kk<16;kk++){ float4 c4=cr[kk];
        acc[kk].x+=e*c4.x; acc[kk].y+=e*c4.y; acc[kk].z+=e*c4.z; acc[kk].w+=e*c4.w; }
    }
  }
  {
    float fac = expf(m_acc - m_run);
    S *= fac;
    #pragma unroll
    for(int kk=0;kk<16;kk++){
      acc[kk].x*=fac; acc[kk].y*=fac; acc[kk].z*=fac; acc[kk].w*=fac;
    }
  }
  for(int st=1; st<=2; st<<=1){
    float mo = __shfl_xor(m_run, st, 64);
    float mc = fmaxf(m_run, mo);
    float fac = expf(m_run - mc);
    S *= fac;
    S += __shfl_xor(S, st, 64);
    #pragma unroll
    for(int kk=0;kk<16;kk++){
      acc[kk].x*=fac; acc[kk].y*=fac; acc[kk].z*=fac; acc[kk].w*=fac;
    }
    #pragma unroll
    for(int kk=0;kk<16;kk++){
      acc[kk].x += __shfl_xor(acc[kk].x,st,64);
      acc[kk].y += __shfl_xor(acc[kk].y,st,64);
      acc[kk].z += __shfl_xor(acc[kk].z,st,64);
      acc[kk].w += __shfl_xor(acc[kk].w,st,64);
    }
    m_run = mc;
  }
  float den = S + EPS_C * ksum_tot[head];
  float dinv = 1.0f/den;
  float4 w0,w1,w2,w3;
  if(fs==0){ w0=acc[0]; w1=acc[1]; w2=acc[2]; w3=acc[3]; }
  else if(fs==1){ w0=acc[4]; w1=acc[5]; w2=acc[6]; w3=acc[7]; }
  else if(fs==2){ w0=acc[8]; w1=acc[9]; w2=acc[10]; w3=acc[11]; }
  else { w0=acc[12]; w1=acc[13]; w2=acc[14]; w3=acc[15]; }
  const float4* ctp = ((const float4*)(ctx_tot + head*64)) + fs*4;
  float4 c0=ctp[0], c1=ctp[1], c2=ctp[2], c3=ctp[3];
  float4* po = (float4*)(pcl + ((size_t)head*T_T + t)*D_H) + fs*4;
  po[0] = make_float4((w0.x+EPS_C*c0.x)*dinv,(w0.y+EPS_C*c0.y)*dinv,(w0.z+EPS_C*c0.z)*dinv,(w0.w+EPS_C*c0.w)*dinv);
  po[1] = make_float4((w1.x+EPS_C*c1.x)*dinv,(w1.y+EPS_C*c1.y)*dinv,(w1.z+EPS_C*c1.z)*dinv,(w1.w+EPS_C*c1.w)*dinv);
  po[2] = make_float4((w2.x+EPS_C*c2.x)*dinv,(w2.y+EPS_C*c2.y)*dinv,(w2.z+EPS_C*c2.z)*dinv,(w2.w+EPS_C*c2.w)*dinv);
  po[3] = make_float4((w3.x+EPS_C*c3.x)*dinv,(w3.y+EPS_C*c3.y)*dinv,(w3.z+EPS_C*c3.z)*dinv,(w3.w+EPS_C*c3.w)*dinv);
}

// ---------------- Kernel D: MLP + LN + GELU + score + softmax -------------
#define FMA4(A,s,W) {A.x+=(s)*W.x; A.y+=(s)*W.y; A.z+=(s)*W.z; A.w+=(s)*W.w;}
__global__ __launch_bounds__(256) void mlp_kern(
    const float* __restrict__ pcl, const float* __restrict__ v,
    const float* __restrict__ mask,
    const float* __restrict__ encw, const float* __restrict__ encb,
    const float* __restrict__ lng, const float* __restrict__ lnb,
    const float* __restrict__ decw, const float* __restrict__ decb,
    float* __restrict__ probsout, float* __restrict__ scoreout){
  int head = blockIdx.x, tblk = blockIdx.y;   // grid (48,32)
  int t0 = tblk*32;
  int n = head / H_H;
  __shared__ float xs[32*132];
  __shared__ float wts[32*132];
  __shared__ float h1s[32*132];
  int colT = threadIdx.x & 15, rowT = threadIdx.x >> 4;
  int r0 = rowT, r1 = rowT + 16;
  const float* pclrow = pcl + ((size_t)head*T_T + t0)*D_H;
  const float* vrow   = v   + ((size_t)head*T_T + t0)*D_H;
  for(int i=threadIdx.x;i<512;i+=256){
    int r=i>>4, q=i&15;
    ((float4*)(xs + r*132))[q]      = ((const float4*)(pclrow + r*64))[q];
    ((float4*)(xs + r*132 + 64))[q] = ((const float4*)(vrow   + r*64))[q];
  }
  float4 bias0 = ((const float4*)encb)[colT];
  float4 bias1 = ((const float4*)encb)[colT+16];
  float4 A0=bias0, A1=bias1, B0=bias0, B1=bias1;
  for(int kc=0;kc<4;kc++){
    __syncthreads();
    for(int i=threadIdx.x;i<1024;i+=256){
      int k=i>>5, q=i&31;
      ((float4*)(wts + k*132))[q] = ((const float4*)(encw + (size_t)(kc*32+k)*128))[q];
    }
    __syncthreads();
    #pragma unroll
    for(int kq=0;kq<8;kq++){
      float4 x0 = ((const float4*)(xs + r0*132 + kc*32))[kq];
      float4 x1 = ((const float4*)(xs + r1*132 + kc*32))[kq];
      #pragma unroll
      for(int kk=0;kk<4;kk++){
        const float* wrow = wts + (kq*4+kk)*132;
        float4 wa = ((const float4*)wrow)[colT];
        float4 wb = ((const float4*)wrow)[colT+16];
        float xv0 = (kk==0)?x0.x:(kk==1)?x0.y:(kk==2)?x0.z:x0.w;
        float xv1 = (kk==0)?x1.x:(kk==1)?x1.y:(kk==2)?x1.z:x1.w;
        FMA4(A0,xv0,wa); FMA4(A1,xv0,wb);
        FMA4(B0,xv1,wa); FMA4(B1,xv1,wb);
      }
    }
  }
  float4 lg0 = ((const float4*)lng)[colT], lg1 = ((const float4*)lng)[colT+16];
  float4 lb0 = ((const float4*)lnb)[colT], lb1 = ((const float4*)lnb)[colT+16];
  float s0 = A0.x+A0.y+A0.z+A0.w + A1.x+A1.y+A1.z+A1.w;
  float s1 = B0.x+B0.y+B0.z+B0.w + B1.x+B1.y+B1.z+B1.w;
  for(int o=1;o<16;o<<=1){ s0 += __shfl_xor(s0,o,64); s1 += __shfl_xor(s1,o,64); }
  float mu0 = s0*(1.0f/128.0f), mu1 = s1*(1.0f/128.0f);
  float v0=0.f, v1=0.f;
  { float d;
    d=A0.x-mu0; v0+=d*d; d=A0.y-mu0; v0+=d*d; d=A0.z-mu0; v0+=d*d; d=A0.w-mu0; v0+=d*d;
    d=A1.x-mu0; v0+=d*d; d=A1.y-mu0; v0+=d*d; d=A1.z-mu0; v0+=d*d; d=A1.w-mu0; v0+=d*d;
    d=B0.x-mu1; v1+=d*d; d=B0.y-mu1; v1+=d*d; d=B0.z-mu1; v1+=d*d; d=B0.w-mu1; v1+=d*d;
    d=B1.x-mu1; v1+=d*d; d=B1.y-mu1; v1+=d*d; d=B1.z-mu1; v1+=d*d; d=B1.w-mu1; v1+=d*d; }
  for(int o=1;o<16;o<<=1){ v0 += __shfl_xor(v0,o,64); v1 += __shfl_xor(v1,o,64); }
  float den0 = sqrtf(v0*(1.0f/128.0f)+1e-5f);
  float den1 = sqrtf(v1*(1.0f/128.0f)+1e-5f);
  #define GELU(x) ((x)*0.5f*(1.0f+erff((x)*0.70710678118654752f)))
  #define LNG(a,mu,dn,g,b) GELU(((a)-(mu))/(dn)*(g)+(b))
  float4 H;
  H.x=LNG(A0.x,mu0,den0,lg0.x,lb0.x); H.y=LNG(A0.y,mu0,den0,lg0.y,lb0.y);
  H.z=LNG(A0.z,mu0,den0,lg0.z,lb0.z); H.w=LNG(A0.w,mu0,den0,lg0.w,lb0.w);
  ((float4*)(h1s + r0*132))[colT] = H;
  H.x=LNG(A1.x,mu0,den0,lg1.x,lb1.x); H.y=LNG(A1.y,mu0,den0,lg1.y,lb1.y);
  H.z=LNG(A1.z,mu0,den0,lg1.z,lb1.z); H.w=LNG(A1.w,mu0,den0,lg1.w,lb1.w);
  ((float4*)(h1s + r0*132))[colT+16] = H;
  H.x=LNG(B0.x,mu1,den1,lg0.x,lb0.x); H.y=LNG(B0.y,mu1,den1,lg0.y,lb0.y);
  H.z=LNG(B0.z,mu1,den1,lg0.z,lb0.z); H.w=LNG(B0.w,mu1,den1,lg0.w,lb0.w);
  ((float4*)(h1s + r1*132))[colT] = H;
  H.x=LNG(B1.x,mu1,den1,lg1.x,lb1.x); H.y=LNG(B1.y,mu1,den1,lg1.y,lb1.y);
  H.z=LNG(B1.z,mu1,den1,lg1.z,lb1.z); H.w=LNG(B1.w,mu1,den1,lg1.w,lb1.w);
  ((float4*)(h1s + r1*132))[colT+16] = H;
  bias0 = ((const float4*)decb)[colT];
  bias1 = ((const float4*)decb)[colT+16];
  A0=bias0; A1=bias1; B0=bias0; B1=bias1;
  for(int kc=0;kc<4;kc++){
    __syncthreads();
    for(int i=threadIdx.x;i<1024;i+=256){
      int k=i>>5, q=i&31;
      ((float4*)(wts + k*132))[q] = ((const float4*)(decw + (size_t)(kc*32+k)*128))[q];
    }
    __syncthreads();
    #pragma unroll
    for(int kq=0;kq<8;kq++){
      float4 x0 = ((const float4*)(h1s + r0*132 + kc*32))[kq];
      float4 x1 = ((const float4*)(h1s + r1*132 + kc*32))[kq];
      #pragma unroll
      for(int kk=0;kk<4;kk++){
        const float* wrow = wts + (kq*4+kk)*132;
        float4 wa = ((const float4*)wrow)[colT];
        float4 wb = ((const float4*)wrow)[colT+16];
        float xv0 = (kk==0)?x0.x:(kk==1)?x0.y:(kk==2)?x0.z:x0.w;
        float xv1 = (kk==0)?x1.x:(kk==1)?x1.y:(kk==2)?x1.z:x1.w;
        FMA4(A0,xv0,wa); FMA4(A1,xv0,wb);
        FMA4(B0,xv1,wa); FMA4(B1,xv1,wb);
      }
    }
  }
  const float* mrow = mask + n*T_T;
  int c0 = colT*4, c1 = colT*4 + 64;
  float rm0[4], rm1[4];
  #pragma unroll
  for(int i=0;i<4;i++){ rm0[i]=mrow[(c0+i)*8]; rm1[i]=mrow[(c1+i)*8]; }
  float sA[8], sB[8];
  sA[0]=(rm0[0]<-1.f)?-10000.f:A0.x; sA[1]=(rm0[1]<-1.f)?-10000.f:A0.y;
  sA[2]=(rm0[2]<-1.f)?-10000.f:A0.z; sA[3]=(rm0[3]<-1.f)?-10000.f:A0.w;
  sA[4]=(rm1[0]<-1.f)?-10000.f:A1.x; sA[5]=(rm1[1]<-1.f)?-10000.f:A1.y;
  sA[6]=(rm1[2]<-1.f)?-10000.f:A1.z; sA[7]=(rm1[3]<-1.f)?-10000.f:A1.w;
  sB[0]=(rm0[0]<-1.f)?-10000.f:B0.x; sB[1]=(rm0[1]<-1.f)?-10000.f:B0.y;
  sB[2]=(rm0[2]<-1.f)?-10000.f:B0.z; sB[3]=(rm0[3]<-1.f)?-10000.f:B0.w;
  sB[4]=(rm1[0]<-1.f)?-10000.f:B1.x; sB[5]=(rm1[1]<-1.f)?-10000.f:B1.y;
  sB[6]=(rm1[2]<-1.f)?-10000.f:B1.z; sB[7]=(rm1[3]<-1.f)?-10000.f:B1.w;
  float mx0=sA[0], mx1=sB[0];
  #pragma unroll
  for(int i=1;i<8;i++){ mx0=fmaxf(mx0,sA[i]); mx1=fmaxf(mx1,sB[i]); }
  for(int o=1;o<16;o<<=1){ mx0=fmaxf(mx0,__shfl_xor(mx0,o,64)); mx1=fmaxf(mx1,__shfl_xor(mx1,o,64)); }
  float Z0=0.f, Z1=0.f;
  #pragma unroll
  for(int i=0;i<8;i++){ sA[i]=expf(sA[i]-mx0); Z0+=sA[i]; sB[i]=expf(sB[i]-mx1); Z1+=sB[i]; }
  for(int o=1;o<16;o<<=1){ Z0+=__shfl_xor(Z0,o,64); Z1+=__shfl_xor(Z1,o,64); }
  float zi0=1.0f/Z0, zi1=1.0f/Z1;
  size_t rb0 = ((size_t)head*T_T + t0 + r0)*TM_;
  size_t rb1 = ((size_t)head*T_T + t0 + r1)*TM_;
  ((float4*)(probsout+rb0))[colT]    = make_float4(sA[0]*zi0,sA[1]*zi0,sA[2]*zi0,sA[3]*zi0);
  ((float4*)(probsout+rb0))[colT+16] = make_float4(sA[4]*zi0,sA[5]*zi0,sA[6]*zi0,sA[7]*zi0);
  ((float4*)(probsout+rb1))[colT]    = make_float4(sB[0]*zi1,sB[1]*zi1,sB[2]*zi1,sB[3]*zi1);
  ((float4*)(probsout+rb1))[colT+16] = make_float4(sB[4]*zi1,sB[5]*zi1,sB[6]*zi1,sB[7]*zi1);
  ((float4*)(scoreout+rb0))[colT]    = A0;
  ((float4*)(scoreout+rb0))[colT+16] = A1;
  ((float4*)(scoreout+rb1))[colT]    = B0;
  ((float4*)(scoreout+rb1))[colT+16] = B1;
}

// ---------------- Kernel E v3: per-row KL + MSE, register-resident --------
__global__ __launch_bounds__(256) void loss_kern(
    const float* __restrict__ truth, const float* __restrict__ mask,
    const float* __restrict__ score, float* __restrict__ klrow,
    float* __restrict__ mserow){
  int row = blockIdx.x;               // head*1024 + t
  int n = row / (H_H*T_T);
  int t = threadIdx.x;
  int lane = t & 63, tq = t >> 6;
  __shared__ float sc[128];
  __shared__ float red[8];
  float4 av  = ((const float4*)(truth + (size_t)row*T_T))[t];
  float4 mkv = ((const float4*)(mask + (size_t)n*T_T))[t];
  if(t < 128) sc[t] = score[(size_t)row*TM_ + t];
  __syncthreads();
  float scv = sc[t>>1];
  float ma = fmaxf(fmaxf(av.x+mkv.x, av.y+mkv.y), fmaxf(av.z+mkv.z, av.w+mkv.w));
  float ms = scv + fmaxf(fmaxf(mkv.x, mkv.y), fmaxf(mkv.z, mkv.w));
  for(int o=32;o;o>>=1){ ma=fmaxf(ma,__shfl_xor(ma,o,64)); ms=fmaxf(ms,__shfl_xor(ms,o,64)); }
  if(lane==0){ red[tq]=ma; red[4+tq]=ms; }
  __syncthreads();
  ma = fmaxf(fmaxf(red[0],red[1]),fmaxf(red[2],red[3]));
  ms = fmaxf(fmaxf(red[4],red[5]),fmaxf(red[6],red[7]));
  __syncthreads();
  float e0=__expf(av.x+mkv.x-ma), e1=__expf(av.y+mkv.y-ma),
        e2=__expf(av.z+mkv.z-ma), e3=__expf(av.w+mkv.w-ma);
  float Za = (e0+e1)+(e2+e3);
  float Zs = (__expf(scv+mkv.x-ms)+__expf(scv+mkv.y-ms))
           + (__expf(scv+mkv.z-ms)+__expf(scv+mkv.w-ms));
  for(int o=32;o;o>>=1){ Za+=__shfl_xor(Za,o,64); Zs+=__shfl_xor(Zs,o,64); }
  if(lane==0){ red[tq]=Za; red[4+tq]=Zs; }
  __syncthreads();
  Za = (red[0]+red[1])+(red[2]+red[3]);
  Zs = (red[4]+red[5])+(red[6]+red[7]);
  __syncthreads();
  float lZs = __logf(Zs), lZa = __logf(Za);
  float invZa = 1.0f/Za;
  float kl=0.f, mse=0.f;
  #define LKL(AJ,MKJ,EJ) { \
    if((MKJ) > -1.0f){ \
      float pt = (EJ)*invZa; \
      float logpt = (pt >= 1e-12f) ? ((AJ)+(MKJ)-ma-lZa) : -27.631021116f; \
      float logp = (scv+(MKJ)-ms) - lZs; \
      kl += pt*(logpt-logp); } \
    float sv = ((MKJ) < -1.0f)?0.f:scv; \
    float avv = ((MKJ) < -1.0f)?0.f:(AJ); \
    float dd = sv-avv; mse += dd*dd; }
  LKL(av.x,mkv.x,e0) LKL(av.y,mkv.y,e1) LKL(av.z,mkv.z,e2) LKL(av.w,mkv.w,e3)
  #undef LKL
  for(int o=32;o;o>>=1){ kl+=__shfl_xor(kl,o,64); mse+=__shfl_xor(mse,o,64); }
  if(lane==0){ red[tq]=kl; red[4+tq]=mse; }
  __syncthreads();
  if(t==0){
    klrow[row]  = (red[0]+red[1])+(red[2]+red[3]);
    mserow[row] = (red[4]+red[5])+(red[6]+red[7]);
  }
}

// ---------------- Kernel F: final loss ------------------------------------
__global__ __launch_bounds__(256) void finloss_kern(
    const float* __restrict__ klrow, const float* __restrict__ mserow,
    const float* __restrict__ mask, float* __restrict__ out0){
  __shared__ double reds[256];
  double kls=0, mses=0;
  for(int i=threadIdx.x;i<N_H*T_T;i+=256){ kls+=(double)klrow[i]; mses+=(double)mserow[i]; }
  double vcnt=0;
  for(int i=threadIdx.x;i<N_B*T_T;i+=256) if(mask[i] > -1.0f) vcnt+=1.0;
  reds[threadIdx.x]=kls; __syncthreads();
  for(int o=128;o;o>>=1){ if(threadIdx.x<o) reds[threadIdx.x]+=reds[threadIdx.x+o]; __syncthreads(); }
  double klsum = reds[0]; __syncthreads();
  reds[threadIdx.x]=mses; __syncthreads();
  for(int o=128;o;o>>=1){ if(threadIdx.x<o) reds[threadIdx.x]+=reds[threadIdx.x+o]; __syncthreads(); }
  double msesum = reds[0]; __syncthreads();
  reds[threadIdx.x]=vcnt; __syncthreads();
  for(int o=128;o;o>>=1){ if(threadIdx.x<o) reds[threadIdx.x]+=reds[threadIdx.x+o]; __syncthreads(); }
  if(threadIdx.x==0){
    double denom = reds[0] * (double)(H_H*T_T);
    double loss = klsum/denom*0.25 + msesum/((double)N_B*H_H*T_T*T_T);
    out0[0]=(float)loss;
  }
}

// ---------------- Top-k pipeline (3 levels: 11/11/10 bits, LDS hist) ------
__global__ __launch_bounds__(256) void topk_init3(
    unsigned* __restrict__ hist, unsigned* __restrict__ state,
    unsigned* __restrict__ tiecnt){
  int i = blockIdx.x*256+threadIdx.x;
  if(i < 4*2048) hist[i]=0u;
  if(i < 4){ state[i*4+0]=0u; state[i*4+1]=KSEL; tiecnt[i]=0u; }
}

__global__ __launch_bounds__(256) void topk_hist3(
    const float* __restrict__ probs, const float* __restrict__ mask,
    const unsigned* __restrict__ state, unsigned* __restrict__ hist, int level){
  __shared__ unsigned lh[4*2048];
  for(int i=threadIdx.x;i<8192;i+=256) lh[i]=0u;
  __syncthreads();
  int shift = (level==0)?21:(level==1)?10:0;
  unsigned mbits = (level==2)?1023u:2047u;
  int topshift = shift + ((level==2)?10:11);   // 32(L0, unused), 21(L1), 10(L2)
  unsigned pref[4];
  for(int b=0;b<4;b++) pref[b]=state[b*4+0];
  size_t total = (size_t)N_B*PER_BATCH;
  for(size_t idx = (size_t)blockIdx.x*256+threadIdx.x; idx < total; idx += (size_t)gridDim.x*256){
    int b = (int)(idx / PER_BATCH);
    unsigned r = (unsigned)(idx - (size_t)b*PER_BATCH);
    int t = (int)((r>>7)&1023u);
    float val = probs[idx];
    if(!(mask[b*T_T+t] > -1.0f)) val = 0.0f;
    unsigned u = __float_as_uint(val);
    bool ok = (level==0) || ((u>>topshift) == (pref[b]>>topshift));
    if(ok) atomicAdd(&lh[b*2048 + ((u>>shift)&mbits)], 1u);
  }
  __syncthreads();
  for(int i=threadIdx.x;i<8192;i+=256){
    unsigned c = lh[i];
    if(c) atomicAdd(&hist[i], c);
  }
}

__global__ __launch_bounds__(256) void topk_scan3(
    unsigned* __restrict__ hist, unsigned* __restrict__ state, int level){
  int b = blockIdx.x;
  unsigned* h = hist + b*2048;
  int shift = (level==0)?21:(level==1)?10:0;
  int nb = (level==2)?1024:2048;
  int per = nb/256;   // 8 or 4
  __shared__ unsigned cs[256];
  unsigned s = 0;
  for(int i=0;i<per;i++) s += h[threadIdx.x*per + i];
  cs[threadIdx.x] = s;
  __syncthreads();
  if(threadIdx.x==0){
    unsigned remk = state[b*4+1];
    unsigned cum = 0; int sc = 0;
    for(int c=255;c>=0;c--){
      unsigned cc = cs[c];
      if(remk <= cum + cc){ sc = c; break; }
      cum += cc;
    }
    int sb = 0;
    for(int bb=per-1;bb>=0;bb--){
      unsigned cc = h[sc*per+bb];
      if(remk <= cum + cc){ sb = bb; break; }
      cum += cc;
    }
    unsigned bin = (unsigned)(sc*per + sb);
    state[b*4+0] |= bin << shift;
    state[b*4+1] = remk - cum;
  }
  __syncthreads();
  for(int i=threadIdx.x;i<2048;i+=256) h[i]=0u;
}

__global__ __launch_bounds__(256) void topk_write(
    const float* __restrict__ probs, const float* __restrict__ mask,
    const unsigned* __restrict__ state, float* __restrict__ pam,
    unsigned* __restrict__ ties, unsigned* __restrict__ tiecnt){
  unsigned thr[4];
  for(int b=0;b<4;b++) thr[b]=state[b*4+0];
  size_t total=(size_t)N_B*PER_BATCH;
  for(size_t idx=(size_t)blockIdx.x*256+threadIdx.x; idx<total; idx += (size_t)gridDim.x*256){
    int b = (int)(idx / PER_BATCH);
    unsigned r = (unsigned)(idx - (size_t)b*PER_BATCH);
    int t = (int)((r>>7)&1023u);
    float val = probs[idx];
    if(!(mask[b*T_T+t] > -1.0f)) val=0.0f;
    unsigned u=__float_as_uint(val);
    float o = -10000.0f;
    if(u > thr[b]) o = 0.0f;
    else if(u == thr[b]){
      unsigned pos = atomicAdd(&tiecnt[b],1u);
      if(pos < 65536u) ties[(size_t)b*65536+pos]=r;
    }
    pam[idx]=o;
  }
}

__global__ __launch_bounds__(256) void topk_ties(
    const unsigned* __restrict__ state, const unsigned* __restrict__ ties,
    const unsigned* __restrict__ tiecnt, float* __restrict__ pam){
  int b = blockIdx.x;
  unsigned needed = state[b*4+1];
  unsigned nt = min(tiecnt[b], 65536u);
  __shared__ unsigned redu[256];
  __shared__ unsigned lohi[2];
  if(threadIdx.x==0){ lohi[0]=0u; lohi[1]=PER_BATCH; }
  __syncthreads();
  if(needed == 0 || nt == 0) return;
  while(true){
    __syncthreads();
    unsigned lo=lohi[0], hi=lohi[1];
    if(hi-lo<=1u) break;
    unsigned mid=(lo+hi)>>1;
    unsigned c=0;
    for(unsigned i=threadIdx.x;i<nt;i+=256) c += (ties[(size_t)b*65536+i] < mid)?1u:0u;
    redu[threadIdx.x]=c; __syncthreads();
    for(int o=128;o;o>>=1){ if(threadIdx.x<o) redu[threadIdx.x]+=redu[threadIdx.x+o]; __syncthreads(); }
    if(threadIdx.x==0){ if(redu[0]>=needed) lohi[1]=mid; else lohi[0]=mid; }
  }
  __syncthreads();
  unsigned X=lohi[1];
  for(unsigned i=threadIdx.x;i<nt;i+=256){
    unsigned r=ties[(size_t)b*65536+i];
    if(r < X) pam[(size_t)b*PER_BATCH + r]=0.0f;
  }
}

// ---------------- launcher ------------------------------------------------
extern "C" void kernel_launch(void* const* d_in, const int* in_sizes, int n_in,
                              void* d_out, int out_size, void* d_ws, size_t ws_size,
                              hipStream_t stream) {
  const float* v     = (const float*)d_in[2];
  const float* qfa   = (const float*)d_in[3];
  const float* kfa   = (const float*)d_in[4];
  const float* mask  = (const float*)d_in[8];
  const float* truth = (const float*)d_in[9];
  const float* pm    = (const float*)d_in[11];
  const float* encw  = (const float*)d_in[12];
  const float* encb  = (const float*)d_in[13];
  const float* lng   = (const float*)d_in[14];
  const float* lnb   = (const float*)d_in[15];
  const float* decw  = (const float*)d_in[16];
  const float* decb  = (const float*)d_in[17];
  float* out = (float*)d_out;
  float* ws  = (float*)d_ws;

  float* ctx     = ws;                              // 817152
  float* ksum    = ctx + (size_t)N_H*F_F*64;        // 12768
  float* klrow   = ksum + N_H*F_F;                  // 49152
  float* mserow  = klrow + N_H*T_T;                 // 49152
  unsigned* hist   = (unsigned*)(mserow + N_H*T_T); // 4*2048 = 8192
  unsigned* state  = hist + 4*2048;                 // 16
  unsigned* tiecnt = state + 16;                    // 4 (+pad)
  unsigned* ties   = tiecnt + 12;                   // 4*65536
  float* ctxraw  = (float*)(ties + (size_t)4*65536);// 817152
  float* ksumP   = ctxraw + (size_t)N_H*F_F*64;     // 12768
  float* mfP     = ksumP + N_H*F_F;                 // 912 (+pad)
  float* ksum_tot= mfP + 1024;                      // 48
  float* ctx_tot = ksum_tot + 48;                   // 3072

  float* pcl   = out + 1;
  float* probs = pcl + (size_t)N_H*T_T*D_H;
  float* pam   = probs + (size_t)N_H*T_T*TM_;

  keyfeat_kern<<<dim3(N_H,NCH),256,0,stream>>>(kfa, pm, mask, ctxraw, ksumP, mfP);
  fixup_kern<<<N_H,256,0,stream>>>(mfP, ksumP, ctxraw, mask, ctx, ksum, ksum_tot, ctx_tot);
  qfeat_kern<<<dim3(N_H,16),256,0,stream>>>(qfa, pm, ctx, ksum, ksum_tot, ctx_tot, pcl);
  mlp_kern<<<dim3(N_H,32),256,0,stream>>>(pcl, v, mask, encw, encb, lng, lnb,
                                          decw, decb, probs, pam /*score*/);
  loss_kern<<<N_H*T_T,256,0,stream>>>(truth, mask, pam /*score*/, klrow, mserow);
  finloss_kern<<<1,256,0,stream>>>(klrow, mserow, mask, out);
  topk_init3<<<32,256,0,stream>>>(hist, state, tiecnt);
  for(int lvl=0;lvl<3;lvl++){
    topk_hist3<<<2048,256,0,stream>>>(probs, mask, state, hist, lvl);
    topk_scan3<<<4,256,0,stream>>>(hist, state, lvl);
  }
  topk_write<<<2048,256,0,stream>>>(probs, mask, state, pam, ties, tiecnt);
  topk_ties<<<4,256,0,stream>>>(state, ties, tiecnt, pam);
}